// Round 1
// baseline (529.899 us; speedup 1.0000x reference)
//
#include <hip/hip_runtime.h>
#include <hip/hip_bf16.h>
#include <stdint.h>

// Problem constants (T5 encoder-decoder block)
#define T5_B   2
#define T5_T   2048
#define T5_S   2048
#define T5_D   768
#define T5_H   12
#define T5_HD  64
#define T5_DFF 3072
#define T5_NB  32
#define NROW   4096   // B*T

typedef __attribute__((ext_vector_type(8))) short bf16x8;
typedef __attribute__((ext_vector_type(4))) float f32x4;

__device__ __forceinline__ unsigned short f2bf(float x) {
  unsigned int u = __float_as_uint(x);
  unsigned int r = (u + 0x7FFFu + ((u >> 16) & 1u)) >> 16;   // RNE
  return (unsigned short)r;
}

__device__ __forceinline__ void load_lds16(const void* g, void* l) {
  __builtin_amdgcn_global_load_lds(
      (__attribute__((address_space(1))) void*)(const_cast<void*>(g)),
      (__attribute__((address_space(3))) void*)(l), 16, 0, 0);
}

// ---------------------------------------------------------------------------
// Weight transpose+convert: W[K][N] f32 -> Wt[N][K] bf16
// ---------------------------------------------------------------------------
__global__ __launch_bounds__(256)
void transpose_w_kernel(const float* __restrict__ W, unsigned short* __restrict__ Wt,
                        int K, int N) {
  __shared__ float tile[32][33];
  int n0 = blockIdx.x * 32, k0 = blockIdx.y * 32;
  int tx = threadIdx.x & 31, ty = threadIdx.x >> 5;  // ty 0..7
#pragma unroll
  for (int i = 0; i < 32; i += 8)
    tile[ty + i][tx] = W[(size_t)(k0 + ty + i) * N + n0 + tx];
  __syncthreads();
#pragma unroll
  for (int i = 0; i < 32; i += 8)
    Wt[(size_t)(n0 + ty + i) * K + k0 + tx] = f2bf(tile[tx][ty + i]);
}

// ---------------------------------------------------------------------------
// RMSNorm (f32 in, bf16 out), D=768, one block per row
// ---------------------------------------------------------------------------
__global__ __launch_bounds__(256)
void rmsnorm_kernel(const float* __restrict__ in, const float* __restrict__ w,
                    unsigned short* __restrict__ out) {
  int row = blockIdx.x, tid = threadIdx.x;
  const float* r = in + (size_t)row * 768;
  float x0 = r[tid], x1 = r[tid + 256], x2 = r[tid + 512];
  float s = x0 * x0 + x1 * x1 + x2 * x2;
#pragma unroll
  for (int off = 32; off > 0; off >>= 1) s += __shfl_xor(s, off);
  __shared__ float ws_[4];
  int lane = tid & 63, wv = tid >> 6;
  if (lane == 0) ws_[wv] = s;
  __syncthreads();
  float tot = ws_[0] + ws_[1] + ws_[2] + ws_[3];
  float rinv = rsqrtf(tot * (1.0f / 768.0f) + 1e-6f);
  unsigned short* o = out + (size_t)row * 768;
  o[tid]       = f2bf(x0 * rinv * w[tid]);
  o[tid + 256] = f2bf(x1 * rinv * w[tid + 256]);
  o[tid + 512] = f2bf(x2 * rinv * w[tid + 512]);
}

// ---------------------------------------------------------------------------
// f32 -> bf16 convert (4 elems/thread)
// ---------------------------------------------------------------------------
__global__ __launch_bounds__(256)
void conv_bf16_kernel(const float* __restrict__ in, unsigned short* __restrict__ out) {
  int i = blockIdx.x * 256 + threadIdx.x;
  float4 v = ((const float4*)in)[i];
  unsigned long long pk = (unsigned long long)f2bf(v.x)
                        | ((unsigned long long)f2bf(v.y) << 16)
                        | ((unsigned long long)f2bf(v.z) << 32)
                        | ((unsigned long long)f2bf(v.w) << 48);
  *(unsigned long long*)(out + (size_t)i * 4) = pk;
}

// ---------------------------------------------------------------------------
// position_bias output: out1[h][t][s] = rel_emb[rp[t][s]][h]
// grid (2, 2048): blockIdx.x = s-half, blockIdx.y = t
// ---------------------------------------------------------------------------
__global__ __launch_bounds__(256)
void pos_bias_kernel(const int* __restrict__ rp, const float* __restrict__ rel_emb,
                     float* __restrict__ out1) {
  __shared__ float rl[384];
  int tid = threadIdx.x;
  for (int i = tid; i < 384; i += 256) rl[i] = rel_emb[i];
  __syncthreads();
  int t = blockIdx.y;
  int s = blockIdx.x * 1024 + tid * 4;
  int4 nb = *(const int4*)(rp + (size_t)t * 2048 + s);
#pragma unroll
  for (int h = 0; h < 12; ++h) {
    float4 v = make_float4(rl[nb.x * 12 + h], rl[nb.y * 12 + h],
                           rl[nb.z * 12 + h], rl[nb.w * 12 + h]);
    *(float4*)(out1 + ((size_t)h * 2048 + t) * 2048 + s) = v;
  }
}

// ---------------------------------------------------------------------------
// V transpose: v [rows=(b*2048+t)][stride, col=h*64+d] bf16 -> vT[(b*12+h)*64+d][2048]
// grid (T/64, H, B)
// ---------------------------------------------------------------------------
__global__ __launch_bounds__(256)
void transpose_v_kernel(const unsigned short* __restrict__ vin, int stride,
                        unsigned short* __restrict__ vT) {
  __shared__ __align__(16) unsigned short tile[64][72];
  int t0 = blockIdx.x * 64, h = blockIdx.y, b = blockIdx.z;
  int tid = threadIdx.x;
  {
    int tl = tid >> 2, d0 = (tid & 3) * 16;
    const unsigned short* src = vin + (size_t)(b * 2048 + t0 + tl) * stride + h * 64 + d0;
    *(bf16x8*)&tile[tl][d0]     = *(const bf16x8*)src;
    *(bf16x8*)&tile[tl][d0 + 8] = *(const bf16x8*)(src + 8);
  }
  __syncthreads();
  {
    int d = tid >> 2, t1 = (tid & 3) * 16;
    unsigned short tmp[16] __attribute__((aligned(16)));
#pragma unroll
    for (int j = 0; j < 16; ++j) tmp[j] = tile[t1 + j][d];
    unsigned short* dst = vT + ((size_t)((b * 12 + h) * 64 + d)) * 2048 + t0 + t1;
    *(bf16x8*)dst       = *(bf16x8*)&tmp[0];
    *(bf16x8*)(dst + 8) = *(bf16x8*)&tmp[8];
  }
}

// ---------------------------------------------------------------------------
// GEMM: C[M=4096][N] = A[4096][K](bf16,row-major) * Bt[N][K](bf16)^T
// 128x128 tile, BK=32, 4 waves (2x2), 16x16x32 MFMA (m97 structure)
// EPI: 0 = bf16 store, 1 = f32 store acc+res, 2 = bf16 store relu(acc)
// ---------------------------------------------------------------------------
template <int EPI>
__global__ __launch_bounds__(256)
void gemm_bt(const unsigned short* __restrict__ A, const unsigned short* __restrict__ Bt,
             void* __restrict__ C, const float* __restrict__ res, int N, int K) {
  __shared__ __align__(16) unsigned short Als[128 * 32];
  __shared__ __align__(16) unsigned short Bls[128 * 32];
  const int tid = threadIdx.x, lane = tid & 63, wv = tid >> 6;
  const int wr = wv >> 1, wc = wv & 1;
  const int m0 = blockIdx.y * 128, n0 = blockIdx.x * 128;

  f32x4 acc[4][4];
#pragma unroll
  for (int i = 0; i < 4; ++i)
#pragma unroll
    for (int j = 0; j < 4; ++j) acc[i][j] = f32x4{0.f, 0.f, 0.f, 0.f};

  const int srow = lane >> 2;           // within-chunk row (+c*16)
  const int sk   = (lane & 3) * 8;      // k offset

  for (int k0 = 0; k0 < K; k0 += 32) {
    __syncthreads();
#pragma unroll
    for (int j = 0; j < 2; ++j) {
      int c = wv * 2 + j;
      load_lds16(A  + (size_t)(m0 + c * 16 + srow) * K + k0 + sk, Als + c * 512);
      load_lds16(Bt + (size_t)(n0 + c * 16 + srow) * K + k0 + sk, Bls + c * 512);
    }
    __syncthreads();
    bf16x8 af[4], bfr[4];
#pragma unroll
    for (int i = 0; i < 4; ++i) {
      af[i]  = *(const bf16x8*)(Als + (size_t)(wr * 64 + i * 16 + (lane & 15)) * 32 + ((lane >> 4) * 8));
      bfr[i] = *(const bf16x8*)(Bls + (size_t)(wc * 64 + i * 16 + (lane & 15)) * 32 + ((lane >> 4) * 8));
    }
#pragma unroll
    for (int i = 0; i < 4; ++i)
#pragma unroll
      for (int j = 0; j < 4; ++j)
        acc[i][j] = __builtin_amdgcn_mfma_f32_16x16x32_bf16(af[i], bfr[j], acc[i][j], 0, 0, 0);
  }

  // epilogue
#pragma unroll
  for (int mi = 0; mi < 4; ++mi)
#pragma unroll
    for (int ni = 0; ni < 4; ++ni) {
      int row = m0 + wr * 64 + mi * 16 + (lane >> 4) * 4;
      int col = n0 + wc * 64 + ni * 16 + (lane & 15);
#pragma unroll
      for (int r = 0; r < 4; ++r) {
        float v = acc[mi][ni][r];
        size_t idx = (size_t)(row + r) * N + col;
        if (EPI == 0) {
          ((unsigned short*)C)[idx] = f2bf(v);
        } else if (EPI == 1) {
          ((float*)C)[idx] = v + res[idx];
        } else {
          ((unsigned short*)C)[idx] = f2bf(fmaxf(v, 0.0f));
        }
      }
    }
}

// ---------------------------------------------------------------------------
// Flash attention. 4 waves x 16 q-rows, KV tiles of 64. 16x16x32 MFMA.
// K_lds / Vt_lds: [64][64] bf16 row-major, XOR swizzle byte ^= ((row&7)<<4),
// staged by global_load_lds with pre-swizzled global source (rule 21).
// SELF: causal + relative-position bias from rp/rel_emb.
// q layout: rows (b*T + t) stride qstride, col h*64+d. k same w/ kstride.
// vT: [(b*12+h)*64 + d][2048].
// ---------------------------------------------------------------------------
template <bool SELF>
__global__ __launch_bounds__(256)
void attn_kernel(const unsigned short* __restrict__ qp, int qstride,
                 const unsigned short* __restrict__ kp, int kstride,
                 const unsigned short* __restrict__ vT,
                 const int* __restrict__ rp, const float* __restrict__ rel_emb,
                 unsigned short* __restrict__ yp) {
  __shared__ __align__(16) unsigned short Kls[64 * 64];
  __shared__ __align__(16) unsigned short Vls[64 * 64];
  __shared__ __align__(16) unsigned short Pls[4 * 16 * 64];
  __shared__ float rel_l[32];

  const int tid = threadIdx.x, lane = tid & 63, wv = tid >> 6;
  const int q0 = blockIdx.x * 64, h = blockIdx.y, b = blockIdx.z;

  if (SELF && tid < 32) rel_l[tid] = rel_emb[tid * 12 + h];

  // Q fragments (A-layout: row = lane&15, k-chunk = (lane>>4)*8)
  const int tq = q0 + wv * 16 + (lane & 15);
  const unsigned short* qr = qp + (size_t)(b * T5_T + tq) * qstride + h * 64 + ((lane >> 4) * 8);
  const bf16x8 qf0 = *(const bf16x8*)qr;
  const bf16x8 qf1 = *(const bf16x8*)(qr + 32);

  f32x4 Oacc[4];
  float m_[4], l_[4];
#pragma unroll
  for (int i = 0; i < 4; ++i) { Oacc[i] = f32x4{0.f, 0.f, 0.f, 0.f}; m_[i] = -3.0e38f; l_[i] = 0.f; }

  const int ntiles = SELF ? (blockIdx.x + 1) : (T5_S / 64);
  unsigned short* Pw = Pls + wv * 1024;

  for (int kt = 0; kt < ntiles; ++kt) {
    const int s0 = kt * 64;
    __syncthreads();
    // stage K and Vt (pre-swizzled source, linear LDS dest)
#pragma unroll
    for (int j = 0; j < 2; ++j) {
      int c = wv * 2 + j;
      int rr = c * 8 + (lane >> 3);
      int d0 = ((lane & 7) ^ (lane >> 3)) * 8;
      load_lds16(kp + (size_t)(b * 2048 + s0 + rr) * kstride + h * 64 + d0, Kls + c * 512);
      load_lds16(vT + (size_t)((b * 12 + h) * 64 + rr) * 2048 + s0 + d0,    Vls + c * 512);
    }
    __syncthreads();

    // QK^T  (S rows = q (D-layout), cols = k)
    f32x4 S[4];
#pragma unroll
    for (int ct = 0; ct < 4; ++ct) {
      int krow = ct * 16 + (lane & 15);
      unsigned by0 = ((unsigned)(krow * 128 + ((lane >> 4) * 16))) ^ ((unsigned)(krow & 7) << 4);
      unsigned by1 = ((unsigned)(krow * 128 + 64 + ((lane >> 4) * 16))) ^ ((unsigned)(krow & 7) << 4);
      bf16x8 kf0 = *(const bf16x8*)((const char*)Kls + by0);
      bf16x8 kf1 = *(const bf16x8*)((const char*)Kls + by1);
      f32x4 sa = f32x4{0.f, 0.f, 0.f, 0.f};
      sa = __builtin_amdgcn_mfma_f32_16x16x32_bf16(qf0, kf0, sa, 0, 0, 0);
      sa = __builtin_amdgcn_mfma_f32_16x16x32_bf16(qf1, kf1, sa, 0, 0, 0);
      S[ct] = sa;
    }

    if (SELF) {
      bool edge = (kt == ntiles - 1);
#pragma unroll
      for (int ct = 0; ct < 4; ++ct) {
        int s = s0 + ct * 16 + (lane & 15);
#pragma unroll
        for (int r = 0; r < 4; ++r) {
          int t = q0 + wv * 16 + (lane >> 4) * 4 + r;
          float sc = S[ct][r] + rel_l[rp[(size_t)t * 2048 + s]];
          if (edge && s > t) sc = -1e30f;
          S[ct][r] = sc;
        }
      }
    }

    // online softmax (rows partitioned: row = (lane>>4)*4 + r)
    float alpha[4];
#pragma unroll
    for (int r = 0; r < 4; ++r) {
      float tm = fmaxf(fmaxf(S[0][r], S[1][r]), fmaxf(S[2][r], S[3][r]));
      tm = fmaxf(tm, __shfl_xor(tm, 1));
      tm = fmaxf(tm, __shfl_xor(tm, 2));
      tm = fmaxf(tm, __shfl_xor(tm, 4));
      tm = fmaxf(tm, __shfl_xor(tm, 8));
      float mn = fmaxf(m_[r], tm);
      alpha[r] = __expf(m_[r] - mn);
#pragma unroll
      for (int ct = 0; ct < 4; ++ct) S[ct][r] = __expf(S[ct][r] - mn);
      float rs = S[0][r] + S[1][r] + S[2][r] + S[3][r];
      rs += __shfl_xor(rs, 1);
      rs += __shfl_xor(rs, 2);
      rs += __shfl_xor(rs, 4);
      rs += __shfl_xor(rs, 8);
      l_[r] = l_[r] * alpha[r] + rs;
      m_[r] = mn;
    }
#pragma unroll
    for (int dt = 0; dt < 4; ++dt)
#pragma unroll
      for (int r = 0; r < 4; ++r) Oacc[dt][r] *= alpha[r];

    // P -> LDS (bf16, swizzled [16][64], per-wave region)
#pragma unroll
    for (int ct = 0; ct < 4; ++ct)
#pragma unroll
      for (int r = 0; r < 4; ++r) {
        int rr = (lane >> 4) * 4 + r;
        int cc = (lane & 15) + 16 * ct;
        unsigned by = ((unsigned)(rr * 128 + cc * 2)) ^ ((unsigned)(rr & 7) << 4);
        *(unsigned short*)((char*)Pw + by) = f2bf(S[ct][r]);
      }
    asm volatile("s_waitcnt lgkmcnt(0)" ::: "memory");
    __builtin_amdgcn_sched_barrier(0);

    // PV
    {
      int prow = lane & 15;
      unsigned pb0 = ((unsigned)(prow * 128 + ((lane >> 4) * 16))) ^ ((unsigned)(prow & 7) << 4);
      unsigned pb1 = ((unsigned)(prow * 128 + 64 + ((lane >> 4) * 16))) ^ ((unsigned)(prow & 7) << 4);
      bf16x8 pf0 = *(const bf16x8*)((const char*)Pw + pb0);
      bf16x8 pf1 = *(const bf16x8*)((const char*)Pw + pb1);
#pragma unroll
      for (int dt = 0; dt < 4; ++dt) {
        int vrow = dt * 16 + (lane & 15);
        unsigned vb0 = ((unsigned)(vrow * 128 + ((lane >> 4) * 16))) ^ ((unsigned)(vrow & 7) << 4);
        unsigned vb1 = ((unsigned)(vrow * 128 + 64 + ((lane >> 4) * 16))) ^ ((unsigned)(vrow & 7) << 4);
        bf16x8 vf0 = *(const bf16x8*)((const char*)Vls + vb0);
        bf16x8 vf1 = *(const bf16x8*)((const char*)Vls + vb1);
        Oacc[dt] = __builtin_amdgcn_mfma_f32_16x16x32_bf16(pf0, vf0, Oacc[dt], 0, 0, 0);
        Oacc[dt] = __builtin_amdgcn_mfma_f32_16x16x32_bf16(pf1, vf1, Oacc[dt], 0, 0, 0);
      }
    }
  }

  // epilogue: normalize, write y (bf16, [4096][768])
#pragma unroll
  for (int r = 0; r < 4; ++r) {
    float inv = 1.0f / l_[r];
    int t = q0 + wv * 16 + (lane >> 4) * 4 + r;
    unsigned short* yr = yp + (size_t)(b * T5_T + t) * 768 + h * 64 + (lane & 15);
#pragma unroll
    for (int dt = 0; dt < 4; ++dt) yr[dt * 16] = f2bf(Oacc[dt][r] * inv);
  }
}

// ---------------------------------------------------------------------------
extern "C" void kernel_launch(void* const* d_in, const int* in_sizes, int n_in,
                              void* d_out, int out_size, void* d_ws, size_t ws_size,
                              hipStream_t stream) {
  (void)in_sizes; (void)n_in; (void)out_size; (void)ws_size;
  const float* x    = (const float*)d_in[0];
  const int*   rp   = (const int*)d_in[2];
  const float* enc  = (const float*)d_in[3];
  const float* sn_w = (const float*)d_in[5];
  const float* wq   = (const float*)d_in[6];
  const float* wk   = (const float*)d_in[7];
  const float* wvw  = (const float*)d_in[8];
  const float* wo   = (const float*)d_in[9];
  const float* rel  = (const float*)d_in[10];
  const float* cn_w = (const float*)d_in[11];
  const float* cwq  = (const float*)d_in[12];
  const float* cwk  = (const float*)d_in[13];
  const float* cwv  = (const float*)d_in[14];
  const float* cwo  = (const float*)d_in[15];
  const float* pn_w = (const float*)d_in[16];
  const float* wi   = (const float*)d_in[17];
  const float* wo2  = (const float*)d_in[18];

  float* out0 = (float*)d_out;
  float* out1 = out0 + (size_t)NROW * T5_D;
  float* out2 = out1 + (size_t)T5_H * T5_T * T5_T;

  char* ws = (char*)d_ws;
  size_t off = 0;
  auto alloc = [&](size_t bytes) { char* p = ws + off; off += (bytes + 255) & ~(size_t)255; return p; };
  unsigned short* wqkvT = (unsigned short*)alloc((size_t)2304 * 768 * 2);
  unsigned short* woT   = (unsigned short*)alloc((size_t)768 * 768 * 2);
  unsigned short* wckvT = (unsigned short*)alloc((size_t)1536 * 768 * 2);
  unsigned short* wcqT  = (unsigned short*)alloc((size_t)768 * 768 * 2);
  unsigned short* wcoT  = (unsigned short*)alloc((size_t)768 * 768 * 2);
  unsigned short* wiT   = (unsigned short*)alloc((size_t)3072 * 768 * 2);
  unsigned short* woT2  = (unsigned short*)alloc((size_t)768 * 3072 * 2);
  unsigned short* normb = (unsigned short*)alloc((size_t)NROW * 768 * 2);
  unsigned short* encb  = (unsigned short*)alloc((size_t)NROW * 768 * 2);
  unsigned short* ybuf  = (unsigned short*)alloc((size_t)NROW * 768 * 2);
  float*          attn  = (float*)alloc((size_t)NROW * 768 * 4);
  unsigned short* big   = (unsigned short*)alloc((size_t)NROW * 3072 * 2);
  unsigned short* vT    = big + (size_t)NROW * 2304;   // 12*2*64*2048 elems, fits in big's tail

  dim3 blk(256);

  // weights -> transposed bf16
  transpose_w_kernel<<<dim3(24, 24), blk, 0, stream>>>(wq,  wqkvT,                 768, 768);
  transpose_w_kernel<<<dim3(24, 24), blk, 0, stream>>>(wk,  wqkvT + 768 * 768,     768, 768);
  transpose_w_kernel<<<dim3(24, 24), blk, 0, stream>>>(wvw, wqkvT + 2 * 768 * 768, 768, 768);
  transpose_w_kernel<<<dim3(24, 24), blk, 0, stream>>>(wo,  woT,                   768, 768);
  transpose_w_kernel<<<dim3(24, 24), blk, 0, stream>>>(cwk, wckvT,                 768, 768);
  transpose_w_kernel<<<dim3(24, 24), blk, 0, stream>>>(cwv, wckvT + 768 * 768,     768, 768);
  transpose_w_kernel<<<dim3(24, 24), blk, 0, stream>>>(cwq, wcqT,                  768, 768);
  transpose_w_kernel<<<dim3(24, 24), blk, 0, stream>>>(cwo, wcoT,                  768, 768);
  transpose_w_kernel<<<dim3(96, 24), blk, 0, stream>>>(wi,  wiT,                   768, 3072);
  transpose_w_kernel<<<dim3(24, 96), blk, 0, stream>>>(wo2, woT2,                  3072, 768);

  // h = rmsnorm(x); enc -> bf16
  rmsnorm_kernel<<<NROW, blk, 0, stream>>>(x, sn_w, normb);
  conv_bf16_kernel<<<3072, blk, 0, stream>>>(enc, encb);

  // QKV projection (concat)  [4096][2304]
  gemm_bt<0><<<dim3(18, 32), blk, 0, stream>>>(normb, wqkvT, big, nullptr, 2304, 768);
  // V transpose for self-attn
  transpose_v_kernel<<<dim3(32, 12, 2), blk, 0, stream>>>(big + 1536, 2304, vT);
  // self-attention (causal + rel bias)
  attn_kernel<true><<<dim3(32, 12, 2), blk, 0, stream>>>(big, 2304, big + 768, 2304, vT, rp, rel, ybuf);
  // O-proj + residual -> attn (f32)
  gemm_bt<1><<<dim3(6, 32), blk, 0, stream>>>(ybuf, woT, attn, x, 768, 768);

  // outputs 1 & 2
  pos_bias_kernel<<<dim3(2, 2048), blk, 0, stream>>>(rp, rel, out1);
  hipMemsetAsync(out2, 0, (size_t)T5_B * T5_T * T5_S * 4, stream);

  // cross-attention
  rmsnorm_kernel<<<NROW, blk, 0, stream>>>(attn, cn_w, normb);
  gemm_bt<0><<<dim3(12, 32), blk, 0, stream>>>(encb, wckvT, big + (size_t)NROW * 768, nullptr, 1536, 768);
  gemm_bt<0><<<dim3(6, 32), blk, 0, stream>>>(normb, wcqT, big, nullptr, 768, 768);
  transpose_v_kernel<<<dim3(32, 12, 2), blk, 0, stream>>>(big + (size_t)NROW * 768 + 768, 1536, vT);
  attn_kernel<false><<<dim3(32, 12, 2), blk, 0, stream>>>(big, 768, big + (size_t)NROW * 768, 1536, vT,
                                                          nullptr, nullptr, ybuf);
  gemm_bt<1><<<dim3(6, 32), blk, 0, stream>>>(ybuf, wcoT, attn, attn, 768, 768);

  // FFN
  rmsnorm_kernel<<<NROW, blk, 0, stream>>>(attn, pn_w, normb);
  gemm_bt<2><<<dim3(24, 32), blk, 0, stream>>>(normb, wiT, big, nullptr, 3072, 768);
  gemm_bt<1><<<dim3(6, 32), blk, 0, stream>>>(big, woT2, out0, attn, 768, 3072);
}

// Round 2
// 513.301 us; speedup vs baseline: 1.0323x; 1.0323x over previous
//
#include <hip/hip_runtime.h>
#include <hip/hip_bf16.h>
#include <stdint.h>

// Problem constants (T5 encoder-decoder block)
#define T5_B   2
#define T5_T   2048
#define T5_S   2048
#define T5_D   768
#define T5_H   12
#define T5_HD  64
#define T5_DFF 3072
#define T5_NB  32
#define NROW   4096   // B*T

typedef __attribute__((ext_vector_type(8))) short bf16x8;
typedef __attribute__((ext_vector_type(4))) float f32x4;

__device__ __forceinline__ unsigned short f2bf(float x) {
  unsigned int u = __float_as_uint(x);
  unsigned int r = (u + 0x7FFFu + ((u >> 16) & 1u)) >> 16;   // RNE
  return (unsigned short)r;
}

__device__ __forceinline__ void load_lds16(const void* g, void* l) {
  __builtin_amdgcn_global_load_lds(
      (__attribute__((address_space(1))) void*)(const_cast<void*>(g)),
      (__attribute__((address_space(3))) void*)(l), 16, 0, 0);
}

// ---------------------------------------------------------------------------
// Weight transpose+convert: W[K][N] f32 -> Wt[N][K] bf16
// ---------------------------------------------------------------------------
__global__ __launch_bounds__(256)
void transpose_w_kernel(const float* __restrict__ W, unsigned short* __restrict__ Wt,
                        int K, int N) {
  __shared__ float tile[32][33];
  int n0 = blockIdx.x * 32, k0 = blockIdx.y * 32;
  int tx = threadIdx.x & 31, ty = threadIdx.x >> 5;  // ty 0..7
#pragma unroll
  for (int i = 0; i < 32; i += 8)
    tile[ty + i][tx] = W[(size_t)(k0 + ty + i) * N + n0 + tx];
  __syncthreads();
#pragma unroll
  for (int i = 0; i < 32; i += 8)
    Wt[(size_t)(n0 + ty + i) * K + k0 + tx] = f2bf(tile[tx][ty + i]);
}

// ---------------------------------------------------------------------------
// RMSNorm (f32 in, bf16 out), D=768, one block per row
// ---------------------------------------------------------------------------
__global__ __launch_bounds__(256)
void rmsnorm_kernel(const float* __restrict__ in, const float* __restrict__ w,
                    unsigned short* __restrict__ out) {
  int row = blockIdx.x, tid = threadIdx.x;
  const float* r = in + (size_t)row * 768;
  float x0 = r[tid], x1 = r[tid + 256], x2 = r[tid + 512];
  float s = x0 * x0 + x1 * x1 + x2 * x2;
#pragma unroll
  for (int off = 32; off > 0; off >>= 1) s += __shfl_xor(s, off);
  __shared__ float ws_[4];
  int lane = tid & 63, wv = tid >> 6;
  if (lane == 0) ws_[wv] = s;
  __syncthreads();
  float tot = ws_[0] + ws_[1] + ws_[2] + ws_[3];
  float rinv = rsqrtf(tot * (1.0f / 768.0f) + 1e-6f);
  unsigned short* o = out + (size_t)row * 768;
  o[tid]       = f2bf(x0 * rinv * w[tid]);
  o[tid + 256] = f2bf(x1 * rinv * w[tid + 256]);
  o[tid + 512] = f2bf(x2 * rinv * w[tid + 512]);
}

// ---------------------------------------------------------------------------
// f32 -> bf16 convert (4 elems/thread)
// ---------------------------------------------------------------------------
__global__ __launch_bounds__(256)
void conv_bf16_kernel(const float* __restrict__ in, unsigned short* __restrict__ out) {
  int i = blockIdx.x * 256 + threadIdx.x;
  float4 v = ((const float4*)in)[i];
  unsigned long long pk = (unsigned long long)f2bf(v.x)
                        | ((unsigned long long)f2bf(v.y) << 16)
                        | ((unsigned long long)f2bf(v.z) << 32)
                        | ((unsigned long long)f2bf(v.w) << 48);
  *(unsigned long long*)(out + (size_t)i * 4) = pk;
}

// ---------------------------------------------------------------------------
// rp (int32) -> permuted uint8 tile-ready buffer.
// Within each 64-col block, byte k at s0+k holds rp[t][s0 + (k>>2) + (k&3)*16].
// So a dword at byte (d*4) = { rp[s0+d], rp[s0+d+16], rp[s0+d+32], rp[s0+d+48] }.
// grid 4096 x 256: idx -> d = idx&15, s0 = ((idx>>4)&31)*64, t = idx>>9
// ---------------------------------------------------------------------------
__global__ __launch_bounds__(256)
void rp8_pack_kernel(const int* __restrict__ rp, unsigned char* __restrict__ rp8p) {
  int idx = blockIdx.x * 256 + threadIdx.x;
  int d = idx & 15;
  int s0 = ((idx >> 4) & 31) * 64;
  int t = idx >> 9;
  const int* r = rp + (size_t)t * 2048 + s0 + d;
  unsigned v0 = (unsigned)r[0] & 31u, v1 = (unsigned)r[16] & 31u,
           v2 = (unsigned)r[32] & 31u, v3 = (unsigned)r[48] & 31u;
  ((unsigned*)(rp8p + (size_t)t * 2048 + s0))[d] = v0 | (v1 << 8) | (v2 << 16) | (v3 << 24);
}

// ---------------------------------------------------------------------------
// position_bias output: out1[h][t][s] = rel_emb[rp[t][s]][h]
// ---------------------------------------------------------------------------
__global__ __launch_bounds__(256)
void pos_bias_kernel(const int* __restrict__ rp, const float* __restrict__ rel_emb,
                     float* __restrict__ out1) {
  __shared__ float rl[384];
  int tid = threadIdx.x;
  for (int i = tid; i < 384; i += 256) rl[i] = rel_emb[i];
  __syncthreads();
  int t = blockIdx.y;
  int s = blockIdx.x * 1024 + tid * 4;
  int4 nb = *(const int4*)(rp + (size_t)t * 2048 + s);
#pragma unroll
  for (int h = 0; h < 12; ++h) {
    float4 v = make_float4(rl[nb.x * 12 + h], rl[nb.y * 12 + h],
                           rl[nb.z * 12 + h], rl[nb.w * 12 + h]);
    *(float4*)(out1 + ((size_t)h * 2048 + t) * 2048 + s) = v;
  }
}

// ---------------------------------------------------------------------------
// V transpose: v[(b*2048+t)*stride + h*64+d] bf16 -> vT[((b*12+h)*64+d)*2048 + t]
// ---------------------------------------------------------------------------
__global__ __launch_bounds__(256)
void transpose_v_kernel(const unsigned short* __restrict__ vin, int stride,
                        unsigned short* __restrict__ vT) {
  __shared__ __align__(16) unsigned short tile[64][72];
  int t0 = blockIdx.x * 64, h = blockIdx.y, b = blockIdx.z;
  int tid = threadIdx.x;
  {
    int tl = tid >> 2, d0 = (tid & 3) * 16;
    const unsigned short* src = vin + (size_t)(b * 2048 + t0 + tl) * stride + h * 64 + d0;
    *(bf16x8*)&tile[tl][d0]     = *(const bf16x8*)src;
    *(bf16x8*)&tile[tl][d0 + 8] = *(const bf16x8*)(src + 8);
  }
  __syncthreads();
  {
    int d = tid >> 2, t1 = (tid & 3) * 16;
    unsigned short tmp[16] __attribute__((aligned(16)));
#pragma unroll
    for (int j = 0; j < 16; ++j) tmp[j] = tile[t1 + j][d];
    unsigned short* dst = vT + ((size_t)((b * 12 + h) * 64 + d)) * 2048 + t0 + t1;
    *(bf16x8*)dst       = *(bf16x8*)&tmp[0];
    *(bf16x8*)(dst + 8) = *(bf16x8*)&tmp[8];
  }
}

// ---------------------------------------------------------------------------
// GEMM: C[M][N] = A[M][K](bf16,row-major) * Bt[N][K](bf16)^T
// TM x TN tile, BK=32, 4 waves, 16x16x32 MFMA.
// TM=128: waves 2x2 (acc 4x4). TM=64: waves 1x4 (acc 4x2).
// EPI: 0 = bf16 store, 1 = f32 store acc+res, 2 = bf16 store relu(acc)
// ---------------------------------------------------------------------------
template <int TM, int TN, int EPI>
__global__ __launch_bounds__(256)
void gemm_bt(const unsigned short* __restrict__ A, const unsigned short* __restrict__ Bt,
             void* __restrict__ C, const float* __restrict__ res, int N, int K) {
  constexpr int WR = (TM >= 128) ? 2 : 1;
  constexpr int WC = 4 / WR;
  constexpr int AM = TM / WR / 16;
  constexpr int AN = TN / WC / 16;
  constexpr int CHA = TM / 16, CHB = TN / 16, CPW = (CHA + CHB) / 4;
  __shared__ __align__(16) unsigned short Als[TM * 32];
  __shared__ __align__(16) unsigned short Bls[TN * 32];
  const int tid = threadIdx.x, lane = tid & 63, wv = tid >> 6;
  const int wr = wv / WC, wc = wv % WC;
  const int m0 = blockIdx.y * TM, n0 = blockIdx.x * TN;

  f32x4 acc[AM][AN];
#pragma unroll
  for (int i = 0; i < AM; ++i)
#pragma unroll
    for (int j = 0; j < AN; ++j) acc[i][j] = f32x4{0.f, 0.f, 0.f, 0.f};

  const int srow = lane >> 2;           // within-chunk row
  const int sk   = (lane & 3) * 8;      // k offset

  for (int k0 = 0; k0 < K; k0 += 32) {
    __syncthreads();
#pragma unroll
    for (int j = 0; j < CPW; ++j) {
      int c = wv * CPW + j;
      if (c < CHA)
        load_lds16(A + (size_t)(m0 + c * 16 + srow) * K + k0 + sk, Als + c * 512);
      else {
        int c2 = c - CHA;
        load_lds16(Bt + (size_t)(n0 + c2 * 16 + srow) * K + k0 + sk, Bls + c2 * 512);
      }
    }
    __syncthreads();
    bf16x8 af[AM], bfr[AN];
#pragma unroll
    for (int i = 0; i < AM; ++i)
      af[i] = *(const bf16x8*)(Als + (size_t)(wr * (AM * 16) + i * 16 + (lane & 15)) * 32 + ((lane >> 4) * 8));
#pragma unroll
    for (int j = 0; j < AN; ++j)
      bfr[j] = *(const bf16x8*)(Bls + (size_t)(wc * (AN * 16) + j * 16 + (lane & 15)) * 32 + ((lane >> 4) * 8));
    __builtin_amdgcn_s_setprio(1);
#pragma unroll
    for (int i = 0; i < AM; ++i)
#pragma unroll
      for (int j = 0; j < AN; ++j)
        acc[i][j] = __builtin_amdgcn_mfma_f32_16x16x32_bf16(af[i], bfr[j], acc[i][j], 0, 0, 0);
    __builtin_amdgcn_s_setprio(0);
  }

  // epilogue
#pragma unroll
  for (int mi = 0; mi < AM; ++mi)
#pragma unroll
    for (int ni = 0; ni < AN; ++ni) {
      int row = m0 + wr * (AM * 16) + mi * 16 + (lane >> 4) * 4;
      int col = n0 + wc * (AN * 16) + ni * 16 + (lane & 15);
#pragma unroll
      for (int r = 0; r < 4; ++r) {
        float v = acc[mi][ni][r];
        size_t idx = (size_t)(row + r) * N + col;
        if (EPI == 0) {
          ((unsigned short*)C)[idx] = f2bf(v);
        } else if (EPI == 1) {
          ((float*)C)[idx] = v + res[idx];
        } else {
          ((unsigned short*)C)[idx] = f2bf(fmaxf(v, 0.0f));
        }
      }
    }
}

// ---------------------------------------------------------------------------
// Flash attention, 2-phase pipelined (double-buffered K/V/rp8 LDS staging).
// 4 waves x 16 q-rows, KV tiles of 64, 16x16x32 MFMA.
// K/Vt LDS: [64][64] bf16, XOR swizzle byte ^= ((row&7)<<4), staged via
// global_load_lds with pre-swizzled global source.
// SELF: causal + relative-position bias via packed rp8p (dword per 4 buckets).
// ---------------------------------------------------------------------------
template <bool SELF>
__global__ __launch_bounds__(256)
void attn_kernel(const unsigned short* __restrict__ qp, int qstride,
                 const unsigned short* __restrict__ kp, int kstride,
                 const unsigned short* __restrict__ vT,
                 const unsigned char* __restrict__ rp8, const float* __restrict__ rel_emb,
                 unsigned short* __restrict__ yp) {
  __shared__ __align__(16) unsigned short Kls[2][64 * 64];
  __shared__ __align__(16) unsigned short Vls[2][64 * 64];
  __shared__ __align__(16) unsigned short Pls[4 * 16 * 64];
  __shared__ __align__(16) unsigned char rp8t[SELF ? 2 * 4096 : 16];
  __shared__ float rel_l[32];

  const int tid = threadIdx.x, lane = tid & 63, wv = tid >> 6;
  const int q0 = blockIdx.x * 64, h = blockIdx.y, b = blockIdx.z;

  if (SELF && tid < 32) rel_l[tid] = rel_emb[tid * 12 + h];

  // Q fragments (A-layout: row = lane&15, k-chunk = (lane>>4)*8)
  const int tq = q0 + wv * 16 + (lane & 15);
  const unsigned short* qr = qp + (size_t)(b * T5_T + tq) * qstride + h * 64 + ((lane >> 4) * 8);
  const bf16x8 qf0 = *(const bf16x8*)qr;
  const bf16x8 qf1 = *(const bf16x8*)(qr + 32);

  f32x4 Oacc[4];
  float m_[4], l_[4];
#pragma unroll
  for (int i = 0; i < 4; ++i) { Oacc[i] = f32x4{0.f, 0.f, 0.f, 0.f}; m_[i] = -3.0e38f; l_[i] = 0.f; }

  const int ntiles = SELF ? (blockIdx.x + 1) : (T5_S / 64);
  unsigned short* Pw = Pls + wv * 1024;

  const int krr = lane >> 3;                 // staging row within 8-row chunk
  const int kd0 = ((lane & 7) ^ krr) * 8;    // pre-swizzled source col

  auto stage = [&](int kt, int bsel) {
    const int s0 = kt * 64;
#pragma unroll
    for (int j = 0; j < 2; ++j) {
      int c = wv * 2 + j;
      int rr = c * 8 + krr;
      load_lds16(kp + (size_t)(b * 2048 + s0 + rr) * kstride + h * 64 + kd0, &Kls[bsel][c * 512]);
      load_lds16(vT + (size_t)((b * 12 + h) * 64 + rr) * 2048 + s0 + kd0,    &Vls[bsel][c * 512]);
    }
    if (SELF)
      load_lds16(rp8 + (size_t)(q0 + wv * 16 + (lane >> 2)) * 2048 + s0 + (lane & 3) * 16,
                 &rp8t[bsel * 4096 + wv * 1024]);
  };

  stage(0, 0);

  for (int kt = 0; kt < ntiles; ++kt) {
    const int bsel = kt & 1;
    const int s0 = kt * 64;
    asm volatile("s_waitcnt vmcnt(0)" ::: "memory");
    __syncthreads();
    if (kt + 1 < ntiles) stage(kt + 1, bsel ^ 1);

    const unsigned short* Kb = &Kls[bsel][0];
    const unsigned short* Vb = &Vls[bsel][0];

    // QK^T  (S rows = q, cols = k)
    f32x4 S[4];
    __builtin_amdgcn_s_setprio(1);
#pragma unroll
    for (int ct = 0; ct < 4; ++ct) {
      int krow = ct * 16 + (lane & 15);
      unsigned by0 = ((unsigned)(krow * 128 + ((lane >> 4) * 16))) ^ ((unsigned)(krow & 7) << 4);
      unsigned by1 = ((unsigned)(krow * 128 + 64 + ((lane >> 4) * 16))) ^ ((unsigned)(krow & 7) << 4);
      bf16x8 kf0 = *(const bf16x8*)((const char*)Kb + by0);
      bf16x8 kf1 = *(const bf16x8*)((const char*)Kb + by1);
      f32x4 sa = f32x4{0.f, 0.f, 0.f, 0.f};
      sa = __builtin_amdgcn_mfma_f32_16x16x32_bf16(qf0, kf0, sa, 0, 0, 0);
      sa = __builtin_amdgcn_mfma_f32_16x16x32_bf16(qf1, kf1, sa, 0, 0, 0);
      S[ct] = sa;
    }
    __builtin_amdgcn_s_setprio(0);

    if (SELF) {
      bool edge = (kt == ntiles - 1);
      const unsigned char* rt = &rp8t[bsel * 4096];
#pragma unroll
      for (int r = 0; r < 4; ++r) {
        int lrow = wv * 16 + (lane >> 4) * 4 + r;
        unsigned nb4 = *(const unsigned*)&rt[lrow * 64 + (lane & 15) * 4];
        int t = q0 + lrow;
#pragma unroll
        for (int ct = 0; ct < 4; ++ct) {
          int s = s0 + ct * 16 + (lane & 15);
          float sc = S[ct][r] + rel_l[(nb4 >> (8 * ct)) & 31u];
          if (edge && s > t) sc = -1e30f;
          S[ct][r] = sc;
        }
      }
    }

    // online softmax (rows partitioned: row = (lane>>4)*4 + r)
    float alpha[4];
#pragma unroll
    for (int r = 0; r < 4; ++r) {
      float tm = fmaxf(fmaxf(S[0][r], S[1][r]), fmaxf(S[2][r], S[3][r]));
      tm = fmaxf(tm, __shfl_xor(tm, 1));
      tm = fmaxf(tm, __shfl_xor(tm, 2));
      tm = fmaxf(tm, __shfl_xor(tm, 4));
      tm = fmaxf(tm, __shfl_xor(tm, 8));
      float mn = fmaxf(m_[r], tm);
      alpha[r] = __expf(m_[r] - mn);
#pragma unroll
      for (int ct = 0; ct < 4; ++ct) S[ct][r] = __expf(S[ct][r] - mn);
      float rs = S[0][r] + S[1][r] + S[2][r] + S[3][r];
      rs += __shfl_xor(rs, 1);
      rs += __shfl_xor(rs, 2);
      rs += __shfl_xor(rs, 4);
      rs += __shfl_xor(rs, 8);
      l_[r] = l_[r] * alpha[r] + rs;
      m_[r] = mn;
    }
#pragma unroll
    for (int dt = 0; dt < 4; ++dt)
#pragma unroll
      for (int r = 0; r < 4; ++r) Oacc[dt][r] *= alpha[r];

    // P -> LDS (bf16, swizzled [16][64], per-wave region)
#pragma unroll
    for (int ct = 0; ct < 4; ++ct)
#pragma unroll
      for (int r = 0; r < 4; ++r) {
        int rr = (lane >> 4) * 4 + r;
        int cc = (lane & 15) + 16 * ct;
        unsigned by = ((unsigned)(rr * 128 + cc * 2)) ^ ((unsigned)(rr & 7) << 4);
        *(unsigned short*)((char*)Pw + by) = f2bf(S[ct][r]);
      }
    asm volatile("s_waitcnt lgkmcnt(0)" ::: "memory");
    __builtin_amdgcn_sched_barrier(0);

    // PV
    {
      int prow = lane & 15;
      unsigned pb0 = ((unsigned)(prow * 128 + ((lane >> 4) * 16))) ^ ((unsigned)(prow & 7) << 4);
      unsigned pb1 = ((unsigned)(prow * 128 + 64 + ((lane >> 4) * 16))) ^ ((unsigned)(prow & 7) << 4);
      bf16x8 pf0 = *(const bf16x8*)((const char*)Pw + pb0);
      bf16x8 pf1 = *(const bf16x8*)((const char*)Pw + pb1);
      __builtin_amdgcn_s_setprio(1);
#pragma unroll
      for (int dt = 0; dt < 4; ++dt) {
        int vrow = dt * 16 + (lane & 15);
        unsigned vb0 = ((unsigned)(vrow * 128 + ((lane >> 4) * 16))) ^ ((unsigned)(vrow & 7) << 4);
        unsigned vb1 = ((unsigned)(vrow * 128 + 64 + ((lane >> 4) * 16))) ^ ((unsigned)(vrow & 7) << 4);
        bf16x8 vf0 = *(const bf16x8*)((const char*)Vb + vb0);
        bf16x8 vf1 = *(const bf16x8*)((const char*)Vb + vb1);
        Oacc[dt] = __builtin_amdgcn_mfma_f32_16x16x32_bf16(pf0, vf0, Oacc[dt], 0, 0, 0);
        Oacc[dt] = __builtin_amdgcn_mfma_f32_16x16x32_bf16(pf1, vf1, Oacc[dt], 0, 0, 0);
      }
      __builtin_amdgcn_s_setprio(0);
    }
  }

  // epilogue: normalize, write y (bf16, [4096][768])
#pragma unroll
  for (int r = 0; r < 4; ++r) {
    float inv = 1.0f / l_[r];
    int t = q0 + wv * 16 + (lane >> 4) * 4 + r;
    unsigned short* yr = yp + (size_t)(b * T5_T + t) * 768 + h * 64 + (lane & 15);
#pragma unroll
    for (int dt = 0; dt < 4; ++dt) yr[dt * 16] = f2bf(Oacc[dt][r] * inv);
  }
}

// ---------------------------------------------------------------------------
extern "C" void kernel_launch(void* const* d_in, const int* in_sizes, int n_in,
                              void* d_out, int out_size, void* d_ws, size_t ws_size,
                              hipStream_t stream) {
  (void)in_sizes; (void)n_in; (void)out_size; (void)ws_size;
  const float* x    = (const float*)d_in[0];
  const int*   rp   = (const int*)d_in[2];
  const float* enc  = (const float*)d_in[3];
  const float* sn_w = (const float*)d_in[5];
  const float* wq   = (const float*)d_in[6];
  const float* wk   = (const float*)d_in[7];
  const float* wvw  = (const float*)d_in[8];
  const float* wo   = (const float*)d_in[9];
  const float* rel  = (const float*)d_in[10];
  const float* cn_w = (const float*)d_in[11];
  const float* cwq  = (const float*)d_in[12];
  const float* cwk  = (const float*)d_in[13];
  const float* cwv  = (const float*)d_in[14];
  const float* cwo  = (const float*)d_in[15];
  const float* pn_w = (const float*)d_in[16];
  const float* wi   = (const float*)d_in[17];
  const float* wo2  = (const float*)d_in[18];

  float* out0 = (float*)d_out;
  float* out1 = out0 + (size_t)NROW * T5_D;
  float* out2 = out1 + (size_t)T5_H * T5_T * T5_T;

  char* ws = (char*)d_ws;
  size_t off = 0;
  auto alloc = [&](size_t bytes) { char* p = ws + off; off += (bytes + 255) & ~(size_t)255; return p; };
  unsigned short* wqkvT = (unsigned short*)alloc((size_t)2304 * 768 * 2);
  unsigned short* woT   = (unsigned short*)alloc((size_t)768 * 768 * 2);
  unsigned short* wckvT = (unsigned short*)alloc((size_t)1536 * 768 * 2);
  unsigned short* wcqT  = (unsigned short*)alloc((size_t)768 * 768 * 2);
  unsigned short* wcoT  = (unsigned short*)alloc((size_t)768 * 768 * 2);
  unsigned short* wiT   = (unsigned short*)alloc((size_t)3072 * 768 * 2);
  unsigned short* woT2  = (unsigned short*)alloc((size_t)768 * 3072 * 2);
  unsigned short* normb = (unsigned short*)alloc((size_t)NROW * 768 * 2);
  unsigned short* encb  = (unsigned short*)alloc((size_t)NROW * 768 * 2);
  unsigned short* ybuf  = (unsigned short*)alloc((size_t)NROW * 768 * 2);
  float*          attn  = (float*)alloc((size_t)NROW * 768 * 4);
  unsigned char*  rp8p  = (unsigned char*)alloc((size_t)2048 * 2048);
  unsigned short* big   = (unsigned short*)alloc((size_t)NROW * 3072 * 2);
  unsigned short* vT    = big + (size_t)NROW * 2304;   // 12*2*64*2048 elems in big's tail

  dim3 blk(256);

  // weights -> transposed bf16
  transpose_w_kernel<<<dim3(24, 24), blk, 0, stream>>>(wq,  wqkvT,                 768, 768);
  transpose_w_kernel<<<dim3(24, 24), blk, 0, stream>>>(wk,  wqkvT + 768 * 768,     768, 768);
  transpose_w_kernel<<<dim3(24, 24), blk, 0, stream>>>(wvw, wqkvT + 2 * 768 * 768, 768, 768);
  transpose_w_kernel<<<dim3(24, 24), blk, 0, stream>>>(wo,  woT,                   768, 768);
  transpose_w_kernel<<<dim3(24, 24), blk, 0, stream>>>(cwk, wckvT,                 768, 768);
  transpose_w_kernel<<<dim3(24, 24), blk, 0, stream>>>(cwv, wckvT + 768 * 768,     768, 768);
  transpose_w_kernel<<<dim3(24, 24), blk, 0, stream>>>(cwq, wcqT,                  768, 768);
  transpose_w_kernel<<<dim3(24, 24), blk, 0, stream>>>(cwo, wcoT,                  768, 768);
  transpose_w_kernel<<<dim3(96, 24), blk, 0, stream>>>(wi,  wiT,                   768, 3072);
  transpose_w_kernel<<<dim3(24, 96), blk, 0, stream>>>(wo2, woT2,                  3072, 768);

  // h = rmsnorm(x); enc -> bf16; rp -> packed u8
  rmsnorm_kernel<<<NROW, blk, 0, stream>>>(x, sn_w, normb);
  conv_bf16_kernel<<<3072, blk, 0, stream>>>(enc, encb);
  rp8_pack_kernel<<<4096, blk, 0, stream>>>(rp, rp8p);

  // QKV projection (concat)  [4096][2304]
  gemm_bt<128, 128, 0><<<dim3(18, 32), blk, 0, stream>>>(normb, wqkvT, big, nullptr, 2304, 768);
  // V transpose for self-attn
  transpose_v_kernel<<<dim3(32, 12, 2), blk, 0, stream>>>(big + 1536, 2304, vT);
  // self-attention (causal + rel bias)
  attn_kernel<true><<<dim3(32, 12, 2), blk, 0, stream>>>(big, 2304, big + 768, 2304, vT, rp8p, rel, ybuf);
  // O-proj + residual -> attn (f32)
  gemm_bt<64, 128, 1><<<dim3(6, 64), blk, 0, stream>>>(ybuf, woT, attn, x, 768, 768);

  // outputs 1 & 2
  pos_bias_kernel<<<dim3(2, 2048), blk, 0, stream>>>(rp, rel, out1);
  hipMemsetAsync(out2, 0, (size_t)T5_B * T5_T * T5_S * 4, stream);

  // cross-attention
  rmsnorm_kernel<<<NROW, blk, 0, stream>>>(attn, cn_w, normb);
  gemm_bt<128, 128, 0><<<dim3(12, 32), blk, 0, stream>>>(encb, wckvT, big + (size_t)NROW * 768, nullptr, 1536, 768);
  gemm_bt<64, 128, 0><<<dim3(6, 64), blk, 0, stream>>>(normb, wcqT, big, nullptr, 768, 768);
  transpose_v_kernel<<<dim3(32, 12, 2), blk, 0, stream>>>(big + (size_t)NROW * 768 + 768, 1536, vT);
  attn_kernel<false><<<dim3(32, 12, 2), blk, 0, stream>>>(big, 768, big + (size_t)NROW * 768, 1536, vT,
                                                          nullptr, nullptr, ybuf);
  gemm_bt<64, 128, 1><<<dim3(6, 64), blk, 0, stream>>>(ybuf, wcoT, attn, attn, 768, 768);

  // FFN
  rmsnorm_kernel<<<NROW, blk, 0, stream>>>(attn, pn_w, normb);
  gemm_bt<128, 128, 2><<<dim3(24, 32), blk, 0, stream>>>(normb, wiT, big, nullptr, 3072, 768);
  gemm_bt<64, 128, 1><<<dim3(6, 64), blk, 0, stream>>>(big, woT2, out0, attn, 768, 3072);
}

// Round 3
// 398.562 us; speedup vs baseline: 1.3295x; 1.2879x over previous
//
#include <hip/hip_runtime.h>
#include <hip/hip_bf16.h>
#include <stdint.h>

// Problem constants (T5 encoder-decoder block)
#define T5_B   2
#define T5_T   2048
#define T5_S   2048
#define T5_D   768
#define T5_H   12
#define T5_HD  64
#define T5_DFF 3072
#define T5_NB  32
#define NROW   4096   // B*T

typedef __attribute__((ext_vector_type(8))) short bf16x8;
typedef __attribute__((ext_vector_type(4))) short short4v;
typedef __attribute__((ext_vector_type(4))) float f32x4;

__device__ __forceinline__ unsigned short f2bf(float x) {
  unsigned int u = __float_as_uint(x);
  unsigned int r = (u + 0x7FFFu + ((u >> 16) & 1u)) >> 16;   // RNE
  return (unsigned short)r;
}

__device__ __forceinline__ void load_lds16(const void* g, void* l) {
  __builtin_amdgcn_global_load_lds(
      (__attribute__((address_space(1))) void*)(const_cast<void*>(g)),
      (__attribute__((address_space(3))) void*)(l), 16, 0, 0);
}

__device__ __forceinline__ unsigned cvt_pk_bf16(float lo_, float hi_) {
  unsigned d;
  asm("v_cvt_pk_bf16_f32 %0, %1, %2" : "=v"(d) : "v"(lo_), "v"(hi_));
  return d;
}

__device__ __forceinline__ f32x4 mfma16(short4v a, short4v b, f32x4 c) {
#if __has_builtin(__builtin_amdgcn_mfma_f32_16x16x16bf16_1k)
  return __builtin_amdgcn_mfma_f32_16x16x16bf16_1k(a, b, c, 0, 0, 0);
#else
  asm volatile("v_mfma_f32_16x16x16_bf16 %0, %1, %2, %0" : "+v"(c) : "v"(a), "v"(b));
  return c;
#endif
}

// ---------------------------------------------------------------------------
// Fused prep kernel: 10 weight transposes (f32 [K][N] -> bf16 [N][K]),
// enc f32->bf16 convert, rp int32 -> u8 pack.
// Block ranges: [0,4608) 8x 768x768; [4608,6912) wi 768x3072;
// [6912,9216) wo2 3072x768; [9216,12288) enc conv; [12288,13312) rp pack.
// ---------------------------------------------------------------------------
struct PrepArgs {
  const float* wsrc[10];
  unsigned short* wdst[10];
  const float* enc; unsigned short* encb;
  const int* rp; unsigned char* rp8;
};

__global__ __launch_bounds__(256)
void prep_kernel(PrepArgs a) {
  __shared__ float tile[32][33];
  const int bid = blockIdx.x, tid = threadIdx.x;
  if (bid < 9216) {
    int widx, rem, Kd, Nd;
    if (bid < 4608)      { widx = bid / 576; rem = bid % 576;  Kd = 768;  Nd = 768;  }
    else if (bid < 6912) { widx = 8;         rem = bid - 4608; Kd = 768;  Nd = 3072; }
    else                 { widx = 9;         rem = bid - 6912; Kd = 3072; Nd = 768;  }
    const float* W = a.wsrc[widx];
    unsigned short* Wt = a.wdst[widx];
    int nb = Nd / 32;
    int n0 = (rem % nb) * 32, k0 = (rem / nb) * 32;
    int tx = tid & 31, ty = tid >> 5;  // ty 0..7
#pragma unroll
    for (int i = 0; i < 32; i += 8)
      tile[ty + i][tx] = W[(size_t)(k0 + ty + i) * Nd + n0 + tx];
    __syncthreads();
#pragma unroll
    for (int i = 0; i < 32; i += 8)
      Wt[(size_t)(n0 + ty + i) * Kd + k0 + tx] = f2bf(tile[tx][ty + i]);
  } else if (bid < 12288) {
    int i = (bid - 9216) * 256 + tid;
    float4 v = ((const float4*)a.enc)[i];
    unsigned long long pk = (unsigned long long)f2bf(v.x)
                          | ((unsigned long long)f2bf(v.y) << 16)
                          | ((unsigned long long)f2bf(v.z) << 32)
                          | ((unsigned long long)f2bf(v.w) << 48);
    *(unsigned long long*)(a.encb + (size_t)i * 4) = pk;
  } else {
    int idx = (bid - 12288) * 256 + tid;          // 16 bytes per thread
    const int4* src = (const int4*)(a.rp + (size_t)idx * 16);
    int4 v0 = src[0], v1 = src[1], v2 = src[2], v3 = src[3];
    uint4 o;
    o.x = (v0.x & 31) | ((v0.y & 31) << 8) | ((v0.z & 31) << 16) | ((v0.w & 31) << 24);
    o.y = (v1.x & 31) | ((v1.y & 31) << 8) | ((v1.z & 31) << 16) | ((v1.w & 31) << 24);
    o.z = (v2.x & 31) | ((v2.y & 31) << 8) | ((v2.z & 31) << 16) | ((v2.w & 31) << 24);
    o.w = (v3.x & 31) | ((v3.y & 31) << 8) | ((v3.z & 31) << 16) | ((v3.w & 31) << 24);
    ((uint4*)a.rp8)[idx] = o;
  }
}

// ---------------------------------------------------------------------------
// RMSNorm (f32 in, bf16 out), D=768, one block per row
// ---------------------------------------------------------------------------
__global__ __launch_bounds__(256)
void rmsnorm_kernel(const float* __restrict__ in, const float* __restrict__ w,
                    unsigned short* __restrict__ out) {
  int row = blockIdx.x, tid = threadIdx.x;
  const float* r = in + (size_t)row * 768;
  float x0 = r[tid], x1 = r[tid + 256], x2 = r[tid + 512];
  float s = x0 * x0 + x1 * x1 + x2 * x2;
#pragma unroll
  for (int off = 32; off > 0; off >>= 1) s += __shfl_xor(s, off);
  __shared__ float ws_[4];
  int lane = tid & 63, wv = tid >> 6;
  if (lane == 0) ws_[wv] = s;
  __syncthreads();
  float tot = ws_[0] + ws_[1] + ws_[2] + ws_[3];
  float rinv = rsqrtf(tot * (1.0f / 768.0f) + 1e-6f);
  unsigned short* o = out + (size_t)row * 768;
  o[tid]       = f2bf(x0 * rinv * w[tid]);
  o[tid + 256] = f2bf(x1 * rinv * w[tid + 256]);
  o[tid + 512] = f2bf(x2 * rinv * w[tid + 512]);
}

// ---------------------------------------------------------------------------
// position_bias output: out1[h][t][s] = rel_emb[rp[t][s]][h]
// ---------------------------------------------------------------------------
__global__ __launch_bounds__(256)
void pos_bias_kernel(const int* __restrict__ rp, const float* __restrict__ rel_emb,
                     float* __restrict__ out1) {
  __shared__ float rl[384];
  int tid = threadIdx.x;
  for (int i = tid; i < 384; i += 256) rl[i] = rel_emb[i];
  __syncthreads();
  int t = blockIdx.y;
  int s = blockIdx.x * 1024 + tid * 4;
  int4 nb = *(const int4*)(rp + (size_t)t * 2048 + s);
#pragma unroll
  for (int h = 0; h < 12; ++h) {
    float4 v = make_float4(rl[nb.x * 12 + h], rl[nb.y * 12 + h],
                           rl[nb.z * 12 + h], rl[nb.w * 12 + h]);
    *(float4*)(out1 + ((size_t)h * 2048 + t) * 2048 + s) = v;
  }
}

// ---------------------------------------------------------------------------
// V transpose: v[(b*2048+t)*stride + h*64+d] bf16 -> vT[((b*12+h)*64+d)*2048 + t]
// ---------------------------------------------------------------------------
__global__ __launch_bounds__(256)
void transpose_v_kernel(const unsigned short* __restrict__ vin, int stride,
                        unsigned short* __restrict__ vT) {
  __shared__ __align__(16) unsigned short tile[64][72];
  int t0 = blockIdx.x * 64, h = blockIdx.y, b = blockIdx.z;
  int tid = threadIdx.x;
  {
    int tl = tid >> 2, d0 = (tid & 3) * 16;
    const unsigned short* src = vin + (size_t)(b * 2048 + t0 + tl) * stride + h * 64 + d0;
    *(bf16x8*)&tile[tl][d0]     = *(const bf16x8*)src;
    *(bf16x8*)&tile[tl][d0 + 8] = *(const bf16x8*)(src + 8);
  }
  __syncthreads();
  {
    int d = tid >> 2, t1 = (tid & 3) * 16;
    unsigned short tmp[16] __attribute__((aligned(16)));
#pragma unroll
    for (int j = 0; j < 16; ++j) tmp[j] = tile[t1 + j][d];
    unsigned short* dst = vT + ((size_t)((b * 12 + h) * 64 + d)) * 2048 + t0 + t1;
    *(bf16x8*)dst       = *(bf16x8*)&tmp[0];
    *(bf16x8*)(dst + 8) = *(bf16x8*)&tmp[8];
  }
}

// ---------------------------------------------------------------------------
// GEMM: C[M][N] = A[M][K](bf16,row-major) * Bt[N][K](bf16)^T
// TM x TN tile, BK=64, XOR-swizzled LDS rows (stride 128B), 4 waves,
// 16x16x32 MFMA. TM=128: waves 2x2 (acc 4x4). TM=64: waves 1x4 (acc 4x2).
// EPI: 0 = bf16 store, 1 = f32 store acc+res, 2 = bf16 store relu(acc)
// ---------------------------------------------------------------------------
template <int TM, int TN, int EPI>
__global__ __launch_bounds__(256)
void gemm_bt(const unsigned short* __restrict__ A, const unsigned short* __restrict__ Bt,
             void* __restrict__ C, const float* __restrict__ res, int N, int K) {
  constexpr int WR = (TM >= 128) ? 2 : 1;
  constexpr int WC = 4 / WR;
  constexpr int AM = TM / WR / 16;
  constexpr int AN = TN / WC / 16;
  constexpr int CHA = TM / 8, CHB = TN / 8, CPW = (CHA + CHB) / 4;
  __shared__ __align__(16) unsigned short Als[TM * 64];
  __shared__ __align__(16) unsigned short Bls[TN * 64];
  const int tid = threadIdx.x, lane = tid & 63, wv = tid >> 6;
  const int lo = lane & 15, hi = lane >> 4;
  const int wr = wv / WC, wc = wv % WC;
  const int m0 = blockIdx.y * TM, n0 = blockIdx.x * TN;

  f32x4 acc[AM][AN];
#pragma unroll
  for (int i = 0; i < AM; ++i)
#pragma unroll
    for (int j = 0; j < AN; ++j) acc[i][j] = f32x4{0.f, 0.f, 0.f, 0.f};

  const int srr  = lane >> 3;                    // row within 8-row chunk
  const int scol = ((lane & 7) ^ srr) * 8;       // pre-swizzled col (halfwords)

  for (int k0 = 0; k0 < K; k0 += 64) {
    __syncthreads();
#pragma unroll
    for (int j = 0; j < CPW; ++j) {
      int c = wv * CPW + j;
      if (c < CHA)
        load_lds16(A + (size_t)(m0 + c * 8 + srr) * K + k0 + scol, Als + c * 512);
      else {
        int c2 = c - CHA;
        load_lds16(Bt + (size_t)(n0 + c2 * 8 + srr) * K + k0 + scol, Bls + c2 * 512);
      }
    }
    __syncthreads();
#pragma unroll
    for (int kk = 0; kk < 2; ++kk) {
      bf16x8 af[AM], bfr[AN];
#pragma unroll
      for (int i = 0; i < AM; ++i) {
        int row = wr * (AM * 16) + i * 16 + lo;
        unsigned by = (unsigned)(row * 128) + ((unsigned)(((kk * 4 + hi) ^ (row & 7))) << 4);
        af[i] = *(const bf16x8*)((const char*)Als + by);
      }
#pragma unroll
      for (int j = 0; j < AN; ++j) {
        int row = wc * (AN * 16) + j * 16 + lo;
        unsigned by = (unsigned)(row * 128) + ((unsigned)(((kk * 4 + hi) ^ (row & 7))) << 4);
        bfr[j] = *(const bf16x8*)((const char*)Bls + by);
      }
      __builtin_amdgcn_s_setprio(1);
#pragma unroll
      for (int i = 0; i < AM; ++i)
#pragma unroll
        for (int j = 0; j < AN; ++j)
          acc[i][j] = __builtin_amdgcn_mfma_f32_16x16x32_bf16(af[i], bfr[j], acc[i][j], 0, 0, 0);
      __builtin_amdgcn_s_setprio(0);
    }
  }

  // epilogue
#pragma unroll
  for (int mi = 0; mi < AM; ++mi)
#pragma unroll
    for (int ni = 0; ni < AN; ++ni) {
      int row = m0 + wr * (AM * 16) + mi * 16 + hi * 4;
      int col = n0 + wc * (AN * 16) + ni * 16 + lo;
#pragma unroll
      for (int r = 0; r < 4; ++r) {
        float v = acc[mi][ni][r];
        size_t idx = (size_t)(row + r) * N + col;
        if (EPI == 0) {
          ((unsigned short*)C)[idx] = f2bf(v);
        } else if (EPI == 1) {
          ((float*)C)[idx] = v + res[idx];
        } else {
          ((unsigned short*)C)[idx] = f2bf(fmaxf(v, 0.0f));
        }
      }
    }
}

// ---------------------------------------------------------------------------
// Flash attention, swapped-operand form. 4 waves x 16 q-rows, KV tiles of 64.
// S^T = mfma_16x16x32(K, Q): lane owns q = lane&15, k = hi*4+r+16ct (16 vals).
// Row stats: in-register + 2 shfls. P feeds PV directly as the B-fragment of
// mfma_16x16x16_bf16 (k-layout matches D-layout: hi*4+{0..3}) -> no P LDS.
// PV swapped: O^T accum (d rows, q cols); A = V^T frags from vT tile.
// K/Vt LDS: [64][64] bf16, XOR swizzle byte ^= ((row&7)<<4), double-buffered,
// staged via global_load_lds with pre-swizzled global source.
// ---------------------------------------------------------------------------
template <bool SELF>
__global__ __launch_bounds__(256)
void attn_kernel(const unsigned short* __restrict__ qp, int qstride,
                 const unsigned short* __restrict__ kp, int kstride,
                 const unsigned short* __restrict__ vT,
                 const unsigned char* __restrict__ rp8, const float* __restrict__ rel_emb,
                 unsigned short* __restrict__ yp) {
  __shared__ __align__(16) unsigned short Kls[2][64 * 64];
  __shared__ __align__(16) unsigned short Vls[2][64 * 64];
  __shared__ __align__(16) unsigned char rp8t[SELF ? 2 * 4096 : 16]; // [bsel][wv*1024 + row*64 + s]
  __shared__ float rel_l[32];

  const int tid = threadIdx.x, lane = tid & 63, wv = tid >> 6;
  const int lo = lane & 15, hi = lane >> 4;
  const int q0 = blockIdx.x * 64, h = blockIdx.y, b = blockIdx.z;

  if (SELF && tid < 32) rel_l[tid] = rel_emb[tid * 12 + h];

  const int q = q0 + wv * 16 + lo;     // this lane's q-row (lane-local!)
  const unsigned short* qr = qp + (size_t)(b * T5_T + q) * qstride + h * 64 + hi * 8;
  const bf16x8 qf0 = *(const bf16x8*)qr;
  const bf16x8 qf1 = *(const bf16x8*)(qr + 32);

  f32x4 Oacc[4];                       // O^T: Oacc[dt][r] = O[dt*16+hi*4+r][q]
#pragma unroll
  for (int i = 0; i < 4; ++i) Oacc[i] = f32x4{0.f, 0.f, 0.f, 0.f};
  float m_ = -3.0e38f, l_ = 0.f;

  const int ntiles = SELF ? (blockIdx.x + 1) : (T5_S / 64);

  const int krr = lane >> 3;                 // staging row within 8-row chunk
  const int kd0 = ((lane & 7) ^ krr) * 8;    // pre-swizzled source col (halfwords)

  auto stage = [&](int kt, int bsel) {
    const int s0 = kt * 64;
#pragma unroll
    for (int j = 0; j < 2; ++j) {
      int c = wv * 2 + j;
      int rr = c * 8 + krr;
      load_lds16(kp + (size_t)(b * 2048 + s0 + rr) * kstride + h * 64 + kd0, &Kls[bsel][c * 512]);
      load_lds16(vT + (size_t)((b * 12 + h) * 64 + rr) * 2048 + s0 + kd0,    &Vls[bsel][c * 512]);
    }
    if (SELF)
      load_lds16(rp8 + (size_t)(q0 + wv * 16 + (lane >> 2)) * 2048 + s0 + (lane & 3) * 16,
                 &rp8t[bsel * 4096 + wv * 1024]);
  };

  stage(0, 0);

  for (int kt = 0; kt < ntiles; ++kt) {
    const int bsel = kt & 1;
    const int s0 = kt * 64;
    asm volatile("s_waitcnt vmcnt(0)" ::: "memory");
    __syncthreads();
    if (kt + 1 < ntiles) stage(kt + 1, bsel ^ 1);

    const unsigned short* Kb = &Kls[bsel][0];
    const unsigned short* Vb = &Vls[bsel][0];

    // QK^T swapped: S[ct][r] = scores[q][s0 + ct*16 + hi*4 + r]
    f32x4 S[4];
    __builtin_amdgcn_s_setprio(1);
#pragma unroll
    for (int ct = 0; ct < 4; ++ct) {
      int krow = ct * 16 + lo;
      unsigned by0 = ((unsigned)(krow * 128 + hi * 16))      ^ ((unsigned)(krow & 7) << 4);
      unsigned by1 = ((unsigned)(krow * 128 + 64 + hi * 16)) ^ ((unsigned)(krow & 7) << 4);
      bf16x8 kf0 = *(const bf16x8*)((const char*)Kb + by0);
      bf16x8 kf1 = *(const bf16x8*)((const char*)Kb + by1);
      f32x4 sa = f32x4{0.f, 0.f, 0.f, 0.f};
      sa = __builtin_amdgcn_mfma_f32_16x16x32_bf16(kf0, qf0, sa, 0, 0, 0);
      sa = __builtin_amdgcn_mfma_f32_16x16x32_bf16(kf1, qf1, sa, 0, 0, 0);
      S[ct] = sa;
    }
    __builtin_amdgcn_s_setprio(0);

    if (SELF) {
      const bool edge = (kt == ntiles - 1);
      const unsigned char* rt = &rp8t[bsel * 4096 + wv * 1024];
#pragma unroll
      for (int ct = 0; ct < 4; ++ct) {
        unsigned nb4 = *(const unsigned*)&rt[lo * 64 + ct * 16 + hi * 4];
#pragma unroll
        for (int r = 0; r < 4; ++r) {
          int s = s0 + ct * 16 + hi * 4 + r;
          float sc = S[ct][r] + rel_l[(nb4 >> (8 * r)) & 31u];
          if (edge && s > q) sc = -1e30f;
          S[ct][r] = sc;
        }
      }
    }

    // online softmax: each lane owns one q-row; reduce across hi groups (2 shfls)
    float tm = S[0][0];
#pragma unroll
    for (int ct = 0; ct < 4; ++ct)
#pragma unroll
      for (int r = 0; r < 4; ++r) tm = fmaxf(tm, S[ct][r]);
    tm = fmaxf(tm, __shfl_xor(tm, 16));
    tm = fmaxf(tm, __shfl_xor(tm, 32));
    float mn = fmaxf(m_, tm);
    float alpha = __expf(m_ - mn);
    float rs = 0.f;
#pragma unroll
    for (int ct = 0; ct < 4; ++ct)
#pragma unroll
      for (int r = 0; r < 4; ++r) { float e = __expf(S[ct][r] - mn); S[ct][r] = e; rs += e; }
    rs += __shfl_xor(rs, 16);
    rs += __shfl_xor(rs, 32);
    l_ = l_ * alpha + rs;
    m_ = mn;
#pragma unroll
    for (int dt = 0; dt < 4; ++dt)
#pragma unroll
      for (int r = 0; r < 4; ++r) Oacc[dt][r] *= alpha;

    // P fragments: bf16 pairs, k = hi*4 + {0..3} per ct -> B-frag of 16x16x16
    short4v pf[4];
#pragma unroll
    for (int ct = 0; ct < 4; ++ct) {
      union { unsigned u[2]; short4v s; } cv;
      cv.u[0] = cvt_pk_bf16(S[ct][0], S[ct][1]);
      cv.u[1] = cvt_pk_bf16(S[ct][2], S[ct][3]);
      pf[ct] = cv.s;
    }

    // PV swapped: Oacc[dt] += V^T[d][s-chunk] * P^T[s-chunk][q]
    __builtin_amdgcn_s_setprio(1);
#pragma unroll
    for (int dt = 0; dt < 4; ++dt) {
      int vrow = dt * 16 + lo;
#pragma unroll
      for (int ct = 0; ct < 4; ++ct) {
        unsigned vb = ((unsigned)(vrow * 128 + ct * 32 + hi * 8)) ^ ((unsigned)(vrow & 7) << 4);
        short4v vf = *(const short4v*)((const char*)Vb + vb);
        Oacc[dt] = mfma16(vf, pf[ct], Oacc[dt]);
      }
    }
    __builtin_amdgcn_s_setprio(0);
  }

#if !__has_builtin(__builtin_amdgcn_mfma_f32_16x16x16bf16_1k)
  asm volatile("s_nop 7\n\ts_nop 7" ::: );
#endif

  // epilogue: O^T -> y[t=q][h*64+d], 4x 8B stores per lane
  float inv = 1.0f / l_;
  unsigned short* yr = yp + (size_t)(b * T5_T + q) * 768 + h * 64 + hi * 4;
#pragma unroll
  for (int dt = 0; dt < 4; ++dt) {
    unsigned long long pk = (unsigned long long)f2bf(Oacc[dt][0] * inv)
                          | ((unsigned long long)f2bf(Oacc[dt][1] * inv) << 16)
                          | ((unsigned long long)f2bf(Oacc[dt][2] * inv) << 32)
                          | ((unsigned long long)f2bf(Oacc[dt][3] * inv) << 48);
    *(unsigned long long*)(yr + dt * 16) = pk;
  }
}

// ---------------------------------------------------------------------------
extern "C" void kernel_launch(void* const* d_in, const int* in_sizes, int n_in,
                              void* d_out, int out_size, void* d_ws, size_t ws_size,
                              hipStream_t stream) {
  (void)in_sizes; (void)n_in; (void)out_size; (void)ws_size;
  const float* x    = (const float*)d_in[0];
  const int*   rp   = (const int*)d_in[2];
  const float* enc  = (const float*)d_in[3];
  const float* sn_w = (const float*)d_in[5];
  const float* wq   = (const float*)d_in[6];
  const float* wk   = (const float*)d_in[7];
  const float* wvw  = (const float*)d_in[8];
  const float* wo   = (const float*)d_in[9];
  const float* rel  = (const float*)d_in[10];
  const float* cn_w = (const float*)d_in[11];
  const float* cwq  = (const float*)d_in[12];
  const float* cwk  = (const float*)d_in[13];
  const float* cwv  = (const float*)d_in[14];
  const float* cwo  = (const float*)d_in[15];
  const float* pn_w = (const float*)d_in[16];
  const float* wi   = (const float*)d_in[17];
  const float* wo2  = (const float*)d_in[18];

  float* out0 = (float*)d_out;
  float* out1 = out0 + (size_t)NROW * T5_D;
  float* out2 = out1 + (size_t)T5_H * T5_T * T5_T;

  char* ws = (char*)d_ws;
  size_t off = 0;
  auto alloc = [&](size_t bytes) { char* p = ws + off; off += (bytes + 255) & ~(size_t)255; return p; };
  unsigned short* wqkvT = (unsigned short*)alloc((size_t)2304 * 768 * 2);
  unsigned short* woT   = (unsigned short*)alloc((size_t)768 * 768 * 2);
  unsigned short* wckvT = (unsigned short*)alloc((size_t)1536 * 768 * 2);
  unsigned short* wcqT  = (unsigned short*)alloc((size_t)768 * 768 * 2);
  unsigned short* wcoT  = (unsigned short*)alloc((size_t)768 * 768 * 2);
  unsigned short* wiT   = (unsigned short*)alloc((size_t)3072 * 768 * 2);
  unsigned short* woT2  = (unsigned short*)alloc((size_t)768 * 3072 * 2);
  unsigned short* normb = (unsigned short*)alloc((size_t)NROW * 768 * 2);
  unsigned short* encb  = (unsigned short*)alloc((size_t)NROW * 768 * 2);
  unsigned short* ybuf  = (unsigned short*)alloc((size_t)NROW * 768 * 2);
  float*          attn  = (float*)alloc((size_t)NROW * 768 * 4);
  unsigned char*  rp8p  = (unsigned char*)alloc((size_t)2048 * 2048);
  unsigned short* big   = (unsigned short*)alloc((size_t)NROW * 3072 * 2);
  unsigned short* vT    = big + (size_t)NROW * 2304;   // 12*2*64*2048 elems in big's tail

  dim3 blk(256);

  // fused prep: weights -> transposed bf16, enc -> bf16, rp -> u8
  {
    PrepArgs pa;
    pa.wsrc[0] = wq;  pa.wdst[0] = wqkvT;
    pa.wsrc[1] = wk;  pa.wdst[1] = wqkvT + 768 * 768;
    pa.wsrc[2] = wvw; pa.wdst[2] = wqkvT + 2 * 768 * 768;
    pa.wsrc[3] = wo;  pa.wdst[3] = woT;
    pa.wsrc[4] = cwk; pa.wdst[4] = wckvT;
    pa.wsrc[5] = cwv; pa.wdst[5] = wckvT + 768 * 768;
    pa.wsrc[6] = cwq; pa.wdst[6] = wcqT;
    pa.wsrc[7] = cwo; pa.wdst[7] = wcoT;
    pa.wsrc[8] = wi;  pa.wdst[8] = wiT;
    pa.wsrc[9] = wo2; pa.wdst[9] = woT2;
    pa.enc = enc; pa.encb = encb; pa.rp = rp; pa.rp8 = rp8p;
    prep_kernel<<<13312, blk, 0, stream>>>(pa);
  }

  // h = rmsnorm(x)
  rmsnorm_kernel<<<NROW, blk, 0, stream>>>(x, sn_w, normb);

  // QKV projection (concat)  [4096][2304]
  gemm_bt<128, 128, 0><<<dim3(18, 32), blk, 0, stream>>>(normb, wqkvT, big, nullptr, 2304, 768);
  // V transpose for self-attn
  transpose_v_kernel<<<dim3(32, 12, 2), blk, 0, stream>>>(big + 1536, 2304, vT);
  // self-attention (causal + rel bias)
  attn_kernel<true><<<dim3(32, 12, 2), blk, 0, stream>>>(big, 2304, big + 768, 2304, vT, rp8p, rel, ybuf);
  // O-proj + residual -> attn (f32)
  gemm_bt<64, 128, 1><<<dim3(6, 64), blk, 0, stream>>>(ybuf, woT, attn, x, 768, 768);

  // outputs 1 & 2
  pos_bias_kernel<<<dim3(2, 2048), blk, 0, stream>>>(rp, rel, out1);
  hipMemsetAsync(out2, 0, (size_t)T5_B * T5_T * T5_S * 4, stream);

  // cross-attention
  rmsnorm_kernel<<<NROW, blk, 0, stream>>>(attn, cn_w, normb);
  gemm_bt<128, 128, 0><<<dim3(12, 32), blk, 0, stream>>>(encb, wckvT, big + (size_t)NROW * 768, nullptr, 1536, 768);
  gemm_bt<64, 128, 0><<<dim3(6, 64), blk, 0, stream>>>(normb, wcqT, big, nullptr, 768, 768);
  transpose_v_kernel<<<dim3(32, 12, 2), blk, 0, stream>>>(big + (size_t)NROW * 768 + 768, 1536, vT);
  attn_kernel<false><<<dim3(32, 12, 2), blk, 0, stream>>>(big, 768, big + (size_t)NROW * 768, 1536, vT,
                                                          nullptr, nullptr, ybuf);
  gemm_bt<64, 128, 1><<<dim3(6, 64), blk, 0, stream>>>(ybuf, wcoT, attn, attn, 768, 768);

  // FFN
  rmsnorm_kernel<<<NROW, blk, 0, stream>>>(attn, pn_w, normb);
  gemm_bt<128, 128, 2><<<dim3(24, 32), blk, 0, stream>>>(normb, wiT, big, nullptr, 3072, 768);
  gemm_bt<64, 128, 1><<<dim3(6, 64), blk, 0, stream>>>(big, woT2, out0, attn, 768, 3072);
}

// Round 4
// 386.924 us; speedup vs baseline: 1.3695x; 1.0301x over previous
//
#include <hip/hip_runtime.h>
#include <hip/hip_bf16.h>
#include <stdint.h>

// Problem constants (T5 encoder-decoder block)
#define T5_B   2
#define T5_T   2048
#define T5_S   2048
#define T5_D   768
#define T5_H   12
#define T5_HD  64
#define T5_DFF 3072
#define T5_NB  32
#define NROW   4096   // B*T

typedef __attribute__((ext_vector_type(8))) short bf16x8;
typedef __attribute__((ext_vector_type(4))) short short4v;
typedef __attribute__((ext_vector_type(4))) float f32x4;

__device__ __forceinline__ unsigned short f2bf(float x) {
  unsigned int u = __float_as_uint(x);
  unsigned int r = (u + 0x7FFFu + ((u >> 16) & 1u)) >> 16;   // RNE
  return (unsigned short)r;
}

__device__ __forceinline__ void load_lds16(const void* g, void* l) {
  __builtin_amdgcn_global_load_lds(
      (__attribute__((address_space(1))) void*)(const_cast<void*>(g)),
      (__attribute__((address_space(3))) void*)(l), 16, 0, 0);
}

__device__ __forceinline__ unsigned cvt_pk_bf16(float lo_, float hi_) {
  unsigned d;
  asm("v_cvt_pk_bf16_f32 %0, %1, %2" : "=v"(d) : "v"(lo_), "v"(hi_));
  return d;
}

__device__ __forceinline__ f32x4 mfma16(short4v a, short4v b, f32x4 c) {
#if __has_builtin(__builtin_amdgcn_mfma_f32_16x16x16bf16_1k)
  return __builtin_amdgcn_mfma_f32_16x16x16bf16_1k(a, b, c, 0, 0, 0);
#else
  asm volatile("v_mfma_f32_16x16x16_bf16 %0, %1, %2, %0" : "+v"(c) : "v"(a), "v"(b));
  return c;
#endif
}

// ---------------------------------------------------------------------------
// Fused prep kernel: 10 weight transposes (f32 [K][N] -> bf16 [N][K]),
// enc f32->bf16 convert, rp int32 -> u8 pack.
// ---------------------------------------------------------------------------
struct PrepArgs {
  const float* wsrc[10];
  unsigned short* wdst[10];
  const float* enc; unsigned short* encb;
  const int* rp; unsigned char* rp8;
};

__global__ __launch_bounds__(256)
void prep_kernel(PrepArgs a) {
  __shared__ float tile[32][33];
  const int bid = blockIdx.x, tid = threadIdx.x;
  if (bid < 9216) {
    int widx, rem, Kd, Nd;
    if (bid < 4608)      { widx = bid / 576; rem = bid % 576;  Kd = 768;  Nd = 768;  }
    else if (bid < 6912) { widx = 8;         rem = bid - 4608; Kd = 768;  Nd = 3072; }
    else                 { widx = 9;         rem = bid - 6912; Kd = 3072; Nd = 768;  }
    const float* W = a.wsrc[widx];
    unsigned short* Wt = a.wdst[widx];
    int nb = Nd / 32;
    int n0 = (rem % nb) * 32, k0 = (rem / nb) * 32;
    int tx = tid & 31, ty = tid >> 5;  // ty 0..7
#pragma unroll
    for (int i = 0; i < 32; i += 8)
      tile[ty + i][tx] = W[(size_t)(k0 + ty + i) * Nd + n0 + tx];
    __syncthreads();
#pragma unroll
    for (int i = 0; i < 32; i += 8)
      Wt[(size_t)(n0 + ty + i) * Kd + k0 + tx] = f2bf(tile[tx][ty + i]);
  } else if (bid < 12288) {
    int i = (bid - 9216) * 256 + tid;
    float4 v = ((const float4*)a.enc)[i];
    unsigned long long pk = (unsigned long long)f2bf(v.x)
                          | ((unsigned long long)f2bf(v.y) << 16)
                          | ((unsigned long long)f2bf(v.z) << 32)
                          | ((unsigned long long)f2bf(v.w) << 48);
    *(unsigned long long*)(a.encb + (size_t)i * 4) = pk;
  } else {
    int idx = (bid - 12288) * 256 + tid;          // 16 bytes per thread
    const int4* src = (const int4*)(a.rp + (size_t)idx * 16);
    int4 v0 = src[0], v1 = src[1], v2 = src[2], v3 = src[3];
    uint4 o;
    o.x = (v0.x & 31) | ((v0.y & 31) << 8) | ((v0.z & 31) << 16) | ((v0.w & 31) << 24);
    o.y = (v1.x & 31) | ((v1.y & 31) << 8) | ((v1.z & 31) << 16) | ((v1.w & 31) << 24);
    o.z = (v2.x & 31) | ((v2.y & 31) << 8) | ((v2.z & 31) << 16) | ((v2.w & 31) << 24);
    o.w = (v3.x & 31) | ((v3.y & 31) << 8) | ((v3.z & 31) << 16) | ((v3.w & 31) << 24);
    ((uint4*)a.rp8)[idx] = o;
  }
}

// ---------------------------------------------------------------------------
// RMSNorm (f32 in, bf16 out), D=768, one block per row
// ---------------------------------------------------------------------------
__global__ __launch_bounds__(256)
void rmsnorm_kernel(const float* __restrict__ in, const float* __restrict__ w,
                    unsigned short* __restrict__ out) {
  int row = blockIdx.x, tid = threadIdx.x;
  const float* r = in + (size_t)row * 768;
  float x0 = r[tid], x1 = r[tid + 256], x2 = r[tid + 512];
  float s = x0 * x0 + x1 * x1 + x2 * x2;
#pragma unroll
  for (int off = 32; off > 0; off >>= 1) s += __shfl_xor(s, off);
  __shared__ float ws_[4];
  int lane = tid & 63, wv = tid >> 6;
  if (lane == 0) ws_[wv] = s;
  __syncthreads();
  float tot = ws_[0] + ws_[1] + ws_[2] + ws_[3];
  float rinv = rsqrtf(tot * (1.0f / 768.0f) + 1e-6f);
  unsigned short* o = out + (size_t)row * 768;
  o[tid]       = f2bf(x0 * rinv * w[tid]);
  o[tid + 256] = f2bf(x1 * rinv * w[tid + 256]);
  o[tid + 512] = f2bf(x2 * rinv * w[tid + 512]);
}

// ---------------------------------------------------------------------------
// position_bias output + out2 zero-fill.
// out1[h][t][s] = rel_emb[rp[t][s]][h];   out2[...] = 0 (8.39M f32)
// grid (2, 2048) x 256
// ---------------------------------------------------------------------------
__global__ __launch_bounds__(256)
void pos_bias_kernel(const int* __restrict__ rp, const float* __restrict__ rel_emb,
                     float* __restrict__ out1, float* __restrict__ out2) {
  __shared__ float rl[384];
  int tid = threadIdx.x;
  for (int i = tid; i < 384; i += 256) rl[i] = rel_emb[i];
  __syncthreads();
  int t = blockIdx.y;
  int s = blockIdx.x * 1024 + tid * 4;
  int4 nb = *(const int4*)(rp + (size_t)t * 2048 + s);
#pragma unroll
  for (int h = 0; h < 12; ++h) {
    float4 v = make_float4(rl[nb.x * 12 + h], rl[nb.y * 12 + h],
                           rl[nb.z * 12 + h], rl[nb.w * 12 + h]);
    *(float4*)(out1 + ((size_t)h * 2048 + t) * 2048 + s) = v;
  }
  // zero out2: 1,048,576 threads x 8 f32
  size_t base = (((size_t)blockIdx.y * 2 + blockIdx.x) * 256 + tid) * 8;
  float4 z = make_float4(0.f, 0.f, 0.f, 0.f);
  *(float4*)(out2 + base)     = z;
  *(float4*)(out2 + base + 4) = z;
}

// ---------------------------------------------------------------------------
// V transpose: v[(b*2048+t)*stride + h*64+d] bf16 -> vT[((b*12+h)*64+d)*2048 + t]
// ---------------------------------------------------------------------------
__global__ __launch_bounds__(256)
void transpose_v_kernel(const unsigned short* __restrict__ vin, int stride,
                        unsigned short* __restrict__ vT) {
  __shared__ __align__(16) unsigned short tile[64][72];
  int t0 = blockIdx.x * 64, h = blockIdx.y, b = blockIdx.z;
  int tid = threadIdx.x;
  {
    int tl = tid >> 2, d0 = (tid & 3) * 16;
    const unsigned short* src = vin + (size_t)(b * 2048 + t0 + tl) * stride + h * 64 + d0;
    *(bf16x8*)&tile[tl][d0]     = *(const bf16x8*)src;
    *(bf16x8*)&tile[tl][d0 + 8] = *(const bf16x8*)(src + 8);
  }
  __syncthreads();
  {
    int d = tid >> 2, t1 = (tid & 3) * 16;
    unsigned short tmp[16] __attribute__((aligned(16)));
#pragma unroll
    for (int j = 0; j < 16; ++j) tmp[j] = tile[t1 + j][d];
    unsigned short* dst = vT + ((size_t)((b * 12 + h) * 64 + d)) * 2048 + t0 + t1;
    *(bf16x8*)dst       = *(bf16x8*)&tmp[0];
    *(bf16x8*)(dst + 8) = *(bf16x8*)&tmp[8];
  }
}

// ---------------------------------------------------------------------------
// GEMM: C[M][N] = A[M][K](bf16,row-major) * Bt[N][K](bf16)^T
// TM x TN tile, BK=64, XOR-swizzled LDS rows, 4 waves, 16x16x32 MFMA.
// Double-buffered LDS + counted vmcnt (T4): stage tile t+1, wait vmcnt(CPW)
// (t's loads only), raw s_barrier (NOT __syncthreads -> would drain prefetch).
// Bijective XCD swizzle (m204) on flattened grid for A-panel L2 locality.
// EPI: 0 = bf16 store, 1 = f32 store acc+res, 2 = bf16 store relu(acc)
// ---------------------------------------------------------------------------
template <int TM, int TN, int EPI>
__global__ __launch_bounds__(256)
void gemm_bt(const unsigned short* __restrict__ A, const unsigned short* __restrict__ Bt,
             void* __restrict__ C, const float* __restrict__ res, int N, int K) {
  constexpr int WR = (TM >= 128) ? 2 : 1;
  constexpr int WC = 4 / WR;
  constexpr int AM = TM / WR / 16;
  constexpr int AN = TN / WC / 16;
  constexpr int CHA = TM / 8, CHB = TN / 8, CPW = (CHA + CHB) / 4;
  __shared__ __align__(16) unsigned short Als[2][TM * 64];
  __shared__ __align__(16) unsigned short Bls[2][TN * 64];
  const int tid = threadIdx.x, lane = tid & 63, wv = tid >> 6;
  const int lo = lane & 15, hi = lane >> 4;
  const int wr = wv / WC, wc = wv % WC;

  // bijective XCD swizzle of flattened block id
  int gx = gridDim.x;
  int nwg = gx * gridDim.y;
  int f = blockIdx.y * gx + blockIdx.x;
  int q8 = nwg >> 3, r8 = nwg & 7, xcd = f & 7, base = f >> 3;
  int wg = (xcd < r8 ? xcd * (q8 + 1) : r8 * (q8 + 1) + (xcd - r8) * q8) + base;
  const int m0 = (wg / gx) * TM, n0 = (wg % gx) * TN;

  f32x4 acc[AM][AN];
#pragma unroll
  for (int i = 0; i < AM; ++i)
#pragma unroll
    for (int j = 0; j < AN; ++j) acc[i][j] = f32x4{0.f, 0.f, 0.f, 0.f};

  const int srr  = lane >> 3;                    // row within 8-row chunk
  const int scol = ((lane & 7) ^ srr) * 8;       // pre-swizzled col (halfwords)

  auto stage = [&](int k0, int bsel) {
#pragma unroll
    for (int j = 0; j < CPW; ++j) {
      int c = wv * CPW + j;
      if (c < CHA)
        load_lds16(A + (size_t)(m0 + c * 8 + srr) * K + k0 + scol, &Als[bsel][c * 512]);
      else {
        int c2 = c - CHA;
        load_lds16(Bt + (size_t)(n0 + c2 * 8 + srr) * K + k0 + scol, &Bls[bsel][c2 * 512]);
      }
    }
  };

  stage(0, 0);
  const int nIt = K >> 6;
  for (int it = 0; it < nIt; ++it) {
    const int bsel = it & 1;
    if (it + 1 < nIt) {
      stage((it + 1) << 6, bsel ^ 1);
      asm volatile("s_waitcnt vmcnt(%0)" :: "n"(CPW) : "memory");
    } else {
      asm volatile("s_waitcnt vmcnt(0)" ::: "memory");
    }
    __builtin_amdgcn_s_barrier();
    __builtin_amdgcn_sched_barrier(0);
#pragma unroll
    for (int kk = 0; kk < 2; ++kk) {
      bf16x8 af[AM], bfr[AN];
#pragma unroll
      for (int i = 0; i < AM; ++i) {
        int row = wr * (AM * 16) + i * 16 + lo;
        unsigned by = (unsigned)(row * 128) + ((unsigned)(((kk * 4 + hi) ^ (row & 7))) << 4);
        af[i] = *(const bf16x8*)((const char*)&Als[bsel][0] + by);
      }
#pragma unroll
      for (int j = 0; j < AN; ++j) {
        int row = wc * (AN * 16) + j * 16 + lo;
        unsigned by = (unsigned)(row * 128) + ((unsigned)(((kk * 4 + hi) ^ (row & 7))) << 4);
        bfr[j] = *(const bf16x8*)((const char*)&Bls[bsel][0] + by);
      }
      __builtin_amdgcn_s_setprio(1);
#pragma unroll
      for (int i = 0; i < AM; ++i)
#pragma unroll
        for (int j = 0; j < AN; ++j)
          acc[i][j] = __builtin_amdgcn_mfma_f32_16x16x32_bf16(af[i], bfr[j], acc[i][j], 0, 0, 0);
      __builtin_amdgcn_s_setprio(0);
    }
    __builtin_amdgcn_sched_barrier(0);
    __builtin_amdgcn_s_barrier();
  }

  // epilogue
#pragma unroll
  for (int mi = 0; mi < AM; ++mi)
#pragma unroll
    for (int ni = 0; ni < AN; ++ni) {
      int row = m0 + wr * (AM * 16) + mi * 16 + hi * 4;
      int col = n0 + wc * (AN * 16) + ni * 16 + lo;
#pragma unroll
      for (int r = 0; r < 4; ++r) {
        float v = acc[mi][ni][r];
        size_t idx = (size_t)(row + r) * N + col;
        if (EPI == 0) {
          ((unsigned short*)C)[idx] = f2bf(v);
        } else if (EPI == 1) {
          ((float*)C)[idx] = v + res[idx];
        } else {
          ((unsigned short*)C)[idx] = f2bf(fmaxf(v, 0.0f));
        }
      }
    }
}

// ---------------------------------------------------------------------------
// Flash attention, swapped-operand, PAIRED q-tiles per block.
// SELF: block x=i owns q-tiles (i, 31-i) -> uniform 33 q-tile computes,
//       K/V staged once for both (kv tiles 0..31-i).
// CROSS: block x=i owns q-tiles (2i, 2i+1), full 32 kv tiles.
// Per q-tile: 4 waves x 16 q-rows. S^T = mfma(K,Q): lane owns q = lane&15.
// P feeds PV in-register as B-frag of 16x16x16 MFMA. O^T accumulated.
// ---------------------------------------------------------------------------
template <bool SELF>
__global__ __launch_bounds__(256)
void attn_kernel(const unsigned short* __restrict__ qp, int qstride,
                 const unsigned short* __restrict__ kp, int kstride,
                 const unsigned short* __restrict__ vT,
                 const unsigned char* __restrict__ rp8, const float* __restrict__ rel_emb,
                 unsigned short* __restrict__ yp) {
  __shared__ __align__(16) unsigned short Kls[2][4096];
  __shared__ __align__(16) unsigned short Vls[2][4096];
  __shared__ __align__(16) unsigned char rp8t[SELF ? 2 * 8192 : 16]; // [bsel][set][wv*1024+row*64+s]
  __shared__ float rel_l[32];

  const int tid = threadIdx.x, lane = tid & 63, wv = tid >> 6;
  const int lo = lane & 15, hi = lane >> 4;
  const int h = blockIdx.y, b = blockIdx.z;
  const int qta = SELF ? (int)blockIdx.x : (int)blockIdx.x * 2;
  const int qtb = SELF ? 31 - (int)blockIdx.x : (int)blockIdx.x * 2 + 1;
  const int ntiles = SELF ? qtb + 1 : 32;

  if (SELF && tid < 32) rel_l[tid] = rel_emb[tid * 12 + h];

  const int qA = qta * 64 + wv * 16 + lo;      // lane-local q rows
  const int qB = qtb * 64 + wv * 16 + lo;
  const unsigned short* qrA = qp + (size_t)(b * T5_T + qA) * qstride + h * 64 + hi * 8;
  const unsigned short* qrB = qp + (size_t)(b * T5_T + qB) * qstride + h * 64 + hi * 8;
  const bf16x8 qa0 = *(const bf16x8*)qrA;
  const bf16x8 qa1 = *(const bf16x8*)(qrA + 32);
  const bf16x8 qb0 = *(const bf16x8*)qrB;
  const bf16x8 qb1 = *(const bf16x8*)(qrB + 32);

  f32x4 OA[4], OB[4];
  float mA = -3.0e38f, lA = 0.f, mB = -3.0e38f, lB = 0.f;
#pragma unroll
  for (int i = 0; i < 4; ++i) { OA[i] = f32x4{0.f, 0.f, 0.f, 0.f}; OB[i] = f32x4{0.f, 0.f, 0.f, 0.f}; }

  const int krr = lane >> 3;
  const int kd0 = ((lane & 7) ^ krr) * 8;

  auto stage = [&](int kt, int bsel) {
    const int s0 = kt * 64;
#pragma unroll
    for (int j = 0; j < 2; ++j) {
      int c = wv * 2 + j;
      int rr = c * 8 + krr;
      load_lds16(kp + (size_t)(b * 2048 + s0 + rr) * kstride + h * 64 + kd0, &Kls[bsel][c * 512]);
      load_lds16(vT + (size_t)((b * 12 + h) * 64 + rr) * 2048 + s0 + kd0,    &Vls[bsel][c * 512]);
    }
    if (SELF) {
      load_lds16(rp8 + (size_t)(qtb * 64 + wv * 16 + (lane >> 2)) * 2048 + s0 + (lane & 3) * 16,
                 &rp8t[bsel * 8192 + 4096 + wv * 1024]);
      if (kt <= qta)
        load_lds16(rp8 + (size_t)(qta * 64 + wv * 16 + (lane >> 2)) * 2048 + s0 + (lane & 3) * 16,
                   &rp8t[bsel * 8192 + wv * 1024]);
    }
  };

  auto qcomp = [&](const bf16x8& qf0, const bf16x8& qf1, f32x4* Oc, float& m_, float& l_,
                   const unsigned char* rt, int qrow, bool edge, int s0,
                   const unsigned short* Kb, const unsigned short* Vb) {
    f32x4 S[4];
    __builtin_amdgcn_s_setprio(1);
#pragma unroll
    for (int ct = 0; ct < 4; ++ct) {
      int krow = ct * 16 + lo;
      unsigned by0 = ((unsigned)(krow * 128 + hi * 16))      ^ ((unsigned)(krow & 7) << 4);
      unsigned by1 = ((unsigned)(krow * 128 + 64 + hi * 16)) ^ ((unsigned)(krow & 7) << 4);
      bf16x8 kf0 = *(const bf16x8*)((const char*)Kb + by0);
      bf16x8 kf1 = *(const bf16x8*)((const char*)Kb + by1);
      f32x4 sa = f32x4{0.f, 0.f, 0.f, 0.f};
      sa = __builtin_amdgcn_mfma_f32_16x16x32_bf16(kf0, qf0, sa, 0, 0, 0);
      sa = __builtin_amdgcn_mfma_f32_16x16x32_bf16(kf1, qf1, sa, 0, 0, 0);
      S[ct] = sa;
    }
    __builtin_amdgcn_s_setprio(0);

    if (SELF) {
#pragma unroll
      for (int ct = 0; ct < 4; ++ct) {
        unsigned nb4 = *(const unsigned*)&rt[lo * 64 + ct * 16 + hi * 4];
#pragma unroll
        for (int r = 0; r < 4; ++r) {
          int s = s0 + ct * 16 + hi * 4 + r;
          float sc = S[ct][r] + rel_l[(nb4 >> (8 * r)) & 31u];
          if (edge && s > qrow) sc = -1e30f;
          S[ct][r] = sc;
        }
      }
    }

    float tm = S[0][0];
#pragma unroll
    for (int ct = 0; ct < 4; ++ct)
#pragma unroll
      for (int r = 0; r < 4; ++r) tm = fmaxf(tm, S[ct][r]);
    tm = fmaxf(tm, __shfl_xor(tm, 16));
    tm = fmaxf(tm, __shfl_xor(tm, 32));
    float mn = fmaxf(m_, tm);
    float alpha = __expf(m_ - mn);
    float rs = 0.f;
#pragma unroll
    for (int ct = 0; ct < 4; ++ct)
#pragma unroll
      for (int r = 0; r < 4; ++r) { float e = __expf(S[ct][r] - mn); S[ct][r] = e; rs += e; }
    rs += __shfl_xor(rs, 16);
    rs += __shfl_xor(rs, 32);
    l_ = l_ * alpha + rs;
    m_ = mn;
#pragma unroll
    for (int dt = 0; dt < 4; ++dt)
#pragma unroll
      for (int r = 0; r < 4; ++r) Oc[dt][r] *= alpha;

    short4v pf[4];
#pragma unroll
    for (int ct = 0; ct < 4; ++ct) {
      union { unsigned u[2]; short4v s; } cv;
      cv.u[0] = cvt_pk_bf16(S[ct][0], S[ct][1]);
      cv.u[1] = cvt_pk_bf16(S[ct][2], S[ct][3]);
      pf[ct] = cv.s;
    }

    __builtin_amdgcn_s_setprio(1);
#pragma unroll
    for (int dt = 0; dt < 4; ++dt) {
      int vrow = dt * 16 + lo;
#pragma unroll
      for (int ct = 0; ct < 4; ++ct) {
        unsigned vb = ((unsigned)(vrow * 128 + ct * 32 + hi * 8)) ^ ((unsigned)(vrow & 7) << 4);
        short4v vf = *(const short4v*)((const char*)Vb + vb);
        Oc[dt] = mfma16(vf, pf[ct], Oc[dt]);
      }
    }
    __builtin_amdgcn_s_setprio(0);
  };

  stage(0, 0);

  for (int kt = 0; kt < ntiles; ++kt) {
    const int bsel = kt & 1;
    const int s0 = kt * 64;
    asm volatile("s_waitcnt vmcnt(0)" ::: "memory");
    __syncthreads();
    if (kt + 1 < ntiles) stage(kt + 1, bsel ^ 1);

    const unsigned short* Kb = &Kls[bsel][0];
    const unsigned short* Vb = &Vls[bsel][0];

    if (!SELF || kt <= qta)
      qcomp(qa0, qa1, OA, mA, lA, &rp8t[bsel * 8192 + wv * 1024], qA,
            SELF && kt == qta, s0, Kb, Vb);
    qcomp(qb0, qb1, OB, mB, lB, &rp8t[bsel * 8192 + 4096 + wv * 1024], qB,
          SELF && kt == qtb, s0, Kb, Vb);
  }

#if !__has_builtin(__builtin_amdgcn_mfma_f32_16x16x16bf16_1k)
  asm volatile("s_nop 7\n\ts_nop 7" ::: );
#endif

  // epilogue: O^T -> y[t=q][h*64+d], 4x 8B stores per lane per q-set
  {
    float inv = 1.0f / lA;
    unsigned short* yr = yp + (size_t)(b * T5_T + qA) * 768 + h * 64 + hi * 4;
#pragma unroll
    for (int dt = 0; dt < 4; ++dt) {
      unsigned long long pk = (unsigned long long)f2bf(OA[dt][0] * inv)
                            | ((unsigned long long)f2bf(OA[dt][1] * inv) << 16)
                            | ((unsigned long long)f2bf(OA[dt][2] * inv) << 32)
                            | ((unsigned long long)f2bf(OA[dt][3] * inv) << 48);
      *(unsigned long long*)(yr + dt * 16) = pk;
    }
  }
  {
    float inv = 1.0f / lB;
    unsigned short* yr = yp + (size_t)(b * T5_T + qB) * 768 + h * 64 + hi * 4;
#pragma unroll
    for (int dt = 0; dt < 4; ++dt) {
      unsigned long long pk = (unsigned long long)f2bf(OB[dt][0] * inv)
                            | ((unsigned long long)f2bf(OB[dt][1] * inv) << 16)
                            | ((unsigned long long)f2bf(OB[dt][2] * inv) << 32)
                            | ((unsigned long long)f2bf(OB[dt][3] * inv) << 48);
      *(unsigned long long*)(yr + dt * 16) = pk;
    }
  }
}

// ---------------------------------------------------------------------------
extern "C" void kernel_launch(void* const* d_in, const int* in_sizes, int n_in,
                              void* d_out, int out_size, void* d_ws, size_t ws_size,
                              hipStream_t stream) {
  (void)in_sizes; (void)n_in; (void)out_size; (void)ws_size;
  const float* x    = (const float*)d_in[0];
  const int*   rp   = (const int*)d_in[2];
  const float* enc  = (const float*)d_in[3];
  const float* sn_w = (const float*)d_in[5];
  const float* wq   = (const float*)d_in[6];
  const float* wk   = (const float*)d_in[7];
  const float* wvw  = (const float*)d_in[8];
  const float* wo   = (const float*)d_in[9];
  const float* rel  = (const float*)d_in[10];
  const float* cn_w = (const float*)d_in[11];
  const float* cwq  = (const float*)d_in[12];
  const float* cwk  = (const float*)d_in[13];
  const float* cwv  = (const float*)d_in[14];
  const float* cwo  = (const float*)d_in[15];
  const float* pn_w = (const float*)d_in[16];
  const float* wi   = (const float*)d_in[17];
  const float* wo2  = (const float*)d_in[18];

  float* out0 = (float*)d_out;
  float* out1 = out0 + (size_t)NROW * T5_D;
  float* out2 = out1 + (size_t)T5_H * T5_T * T5_T;

  char* ws = (char*)d_ws;
  size_t off = 0;
  auto alloc = [&](size_t bytes) { char* p = ws + off; off += (bytes + 255) & ~(size_t)255; return p; };
  unsigned short* wqkvT = (unsigned short*)alloc((size_t)2304 * 768 * 2);
  unsigned short* woT   = (unsigned short*)alloc((size_t)768 * 768 * 2);
  unsigned short* wckvT = (unsigned short*)alloc((size_t)1536 * 768 * 2);
  unsigned short* wcqT  = (unsigned short*)alloc((size_t)768 * 768 * 2);
  unsigned short* wcoT  = (unsigned short*)alloc((size_t)768 * 768 * 2);
  unsigned short* wiT   = (unsigned short*)alloc((size_t)3072 * 768 * 2);
  unsigned short* woT2  = (unsigned short*)alloc((size_t)768 * 3072 * 2);
  unsigned short* normb = (unsigned short*)alloc((size_t)NROW * 768 * 2);
  unsigned short* encb  = (unsigned short*)alloc((size_t)NROW * 768 * 2);
  unsigned short* ybuf  = (unsigned short*)alloc((size_t)NROW * 768 * 2);
  float*          attn  = (float*)alloc((size_t)NROW * 768 * 4);
  unsigned char*  rp8p  = (unsigned char*)alloc((size_t)2048 * 2048);
  unsigned short* big   = (unsigned short*)alloc((size_t)NROW * 3072 * 2);
  unsigned short* vT    = big + (size_t)NROW * 2304;   // 12*2*64*2048 elems in big's tail

  dim3 blk(256);

  // fused prep: weights -> transposed bf16, enc -> bf16, rp -> u8
  {
    PrepArgs pa;
    pa.wsrc[0] = wq;  pa.wdst[0] = wqkvT;
    pa.wsrc[1] = wk;  pa.wdst[1] = wqkvT + 768 * 768;
    pa.wsrc[2] = wvw; pa.wdst[2] = wqkvT + 2 * 768 * 768;
    pa.wsrc[3] = wo;  pa.wdst[3] = woT;
    pa.wsrc[4] = cwk; pa.wdst[4] = wckvT;
    pa.wsrc[5] = cwv; pa.wdst[5] = wckvT + 768 * 768;
    pa.wsrc[6] = cwq; pa.wdst[6] = wcqT;
    pa.wsrc[7] = cwo; pa.wdst[7] = wcoT;
    pa.wsrc[8] = wi;  pa.wdst[8] = wiT;
    pa.wsrc[9] = wo2; pa.wdst[9] = woT2;
    pa.enc = enc; pa.encb = encb; pa.rp = rp; pa.rp8 = rp8p;
    prep_kernel<<<13312, blk, 0, stream>>>(pa);
  }

  // h = rmsnorm(x)
  rmsnorm_kernel<<<NROW, blk, 0, stream>>>(x, sn_w, normb);

  // QKV projection (concat)  [4096][2304]
  gemm_bt<128, 128, 0><<<dim3(18, 32), blk, 0, stream>>>(normb, wqkvT, big, nullptr, 2304, 768);
  // V transpose for self-attn
  transpose_v_kernel<<<dim3(32, 12, 2), blk, 0, stream>>>(big + 1536, 2304, vT);
  // self-attention (causal + rel bias), paired q-tiles
  attn_kernel<true><<<dim3(16, 12, 2), blk, 0, stream>>>(big, 2304, big + 768, 2304, vT, rp8p, rel, ybuf);
  // O-proj + residual -> attn (f32)
  gemm_bt<64, 128, 1><<<dim3(6, 64), blk, 0, stream>>>(ybuf, woT, attn, x, 768, 768);

  // outputs 1 & 2 (fused)
  pos_bias_kernel<<<dim3(2, 2048), blk, 0, stream>>>(rp, rel, out1, out2);

  // cross-attention
  rmsnorm_kernel<<<NROW, blk, 0, stream>>>(attn, cn_w, normb);
  gemm_bt<128, 128, 0><<<dim3(12, 32), blk, 0, stream>>>(encb, wckvT, big + (size_t)NROW * 768, nullptr, 1536, 768);
  gemm_bt<64, 128, 0><<<dim3(6, 64), blk, 0, stream>>>(normb, wcqT, big, nullptr, 768, 768);
  transpose_v_kernel<<<dim3(32, 12, 2), blk, 0, stream>>>(big + (size_t)NROW * 768 + 768, 1536, vT);
  attn_kernel<false><<<dim3(16, 12, 2), blk, 0, stream>>>(big, 768, big + (size_t)NROW * 768, 1536, vT,
                                                          nullptr, nullptr, ybuf);
  gemm_bt<64, 128, 1><<<dim3(6, 64), blk, 0, stream>>>(ybuf, wcoT, attn, attn, 768, 768);

  // FFN
  rmsnorm_kernel<<<NROW, blk, 0, stream>>>(attn, pn_w, normb);
  gemm_bt<128, 128, 2><<<dim3(24, 32), blk, 0, stream>>>(normb, wiT, big, nullptr, 3072, 768);
  gemm_bt<64, 128, 1><<<dim3(6, 64), blk, 0, stream>>>(big, woT2, out0, attn, 768, 3072);
}

// Round 5
// 360.804 us; speedup vs baseline: 1.4687x; 1.0724x over previous
//
#include <hip/hip_runtime.h>
#include <hip/hip_bf16.h>
#include <stdint.h>

// Problem constants (T5 encoder-decoder block)
#define T5_B   2
#define T5_T   2048
#define T5_S   2048
#define T5_D   768
#define T5_H   12
#define T5_HD  64
#define T5_DFF 3072
#define T5_NB  32
#define NROW   4096   // B*T

typedef __attribute__((ext_vector_type(8))) short bf16x8;
typedef __attribute__((ext_vector_type(4))) short short4v;
typedef __attribute__((ext_vector_type(4))) float f32x4;

__device__ __forceinline__ unsigned short f2bf(float x) {
  unsigned int u = __float_as_uint(x);
  unsigned int r = (u + 0x7FFFu + ((u >> 16) & 1u)) >> 16;   // RNE
  return (unsigned short)r;
}

__device__ __forceinline__ void load_lds16(const void* g, void* l) {
  __builtin_amdgcn_global_load_lds(
      (__attribute__((address_space(1))) void*)(const_cast<void*>(g)),
      (__attribute__((address_space(3))) void*)(l), 16, 0, 0);
}

__device__ __forceinline__ unsigned cvt_pk_bf16(float lo_, float hi_) {
  unsigned d;
  asm("v_cvt_pk_bf16_f32 %0, %1, %2" : "=v"(d) : "v"(lo_), "v"(hi_));
  return d;
}

__device__ __forceinline__ f32x4 mfma16(short4v a, short4v b, f32x4 c) {
#if __has_builtin(__builtin_amdgcn_mfma_f32_16x16x16bf16_1k)
  return __builtin_amdgcn_mfma_f32_16x16x16bf16_1k(a, b, c, 0, 0, 0);
#else
  asm volatile("v_mfma_f32_16x16x16_bf16 %0, %1, %2, %0" : "+v"(c) : "v"(a), "v"(b));
  return c;
#endif
}

// bijective XCD chunk swizzle (m204): 8 XCDs, contiguous chunk per XCD
__device__ __forceinline__ int xcd_swz(int f, int nwg) {
  int q8 = nwg >> 3, r8 = nwg & 7, xcd = f & 7, base = f >> 3;
  return (xcd < r8 ? xcd * (q8 + 1) : r8 * (q8 + 1) + (xcd - r8) * q8) + base;
}

// ---------------------------------------------------------------------------
// GEMM body: C[M][N] = A[M][K](bf16) * Bt[N][K](bf16)^T.
// TM x TN tile, BK=64, XOR-swizzled LDS rows, 4 waves, 16x16x32 MFMA.
// Double-buffered + counted vmcnt: stage t+1 before waiting; wait vmcnt(CPW)
// so t+1's loads stay in flight across the raw s_barrier.
// EPI: 0 = bf16 store, 1 = f32 store acc+res, 2 = bf16 store relu(acc)
// ---------------------------------------------------------------------------
template <int TM, int TN, int EPI>
__device__ __forceinline__ void gemm_body(
    int f, int gx, int nwg,
    const unsigned short* __restrict__ A, const unsigned short* __restrict__ Bt,
    void* __restrict__ C, const float* __restrict__ res, int N, int K,
    unsigned short* LDS) {
  constexpr int WR = (TM >= 128) ? 2 : 1;
  constexpr int WC = 4 / WR;
  constexpr int AM = TM / WR / 16;
  constexpr int AN = TN / WC / 16;
  constexpr int CHA = TM / 8, CHB = TN / 8, CPW = (CHA + CHB) / 4;
  constexpr int BUFSH = (TM + TN) * 64;   // shorts per buffer
  const int tid = threadIdx.x, lane = tid & 63, wv = tid >> 6;
  const int lo = lane & 15, hi = lane >> 4;
  const int wr = wv / WC, wc = wv % WC;
  const int wg = xcd_swz(f, nwg);
  const int m0 = (wg / gx) * TM, n0 = (wg % gx) * TN;

  f32x4 acc[AM][AN];
#pragma unroll
  for (int i = 0; i < AM; ++i)
#pragma unroll
    for (int j = 0; j < AN; ++j) acc[i][j] = f32x4{0.f, 0.f, 0.f, 0.f};

  const int srr  = lane >> 3;                    // row within 8-row chunk
  const int scol = ((lane & 7) ^ srr) * 8;       // pre-swizzled col (halfwords)

  auto stage = [&](int k0, int bsel) {
    unsigned short* Ab = LDS + bsel * BUFSH;
    unsigned short* Bb = Ab + TM * 64;
#pragma unroll
    for (int j = 0; j < CPW; ++j) {
      int c = wv * CPW + j;
      if (c < CHA)
        load_lds16(A + (size_t)(m0 + c * 8 + srr) * K + k0 + scol, Ab + c * 512);
      else {
        int c2 = c - CHA;
        load_lds16(Bt + (size_t)(n0 + c2 * 8 + srr) * K + k0 + scol, Bb + c2 * 512);
      }
    }
  };

  stage(0, 0);
  const int nIt = K >> 6;
  for (int it = 0; it < nIt; ++it) {
    const int bsel = it & 1;
    if (it + 1 < nIt) {
      stage((it + 1) << 6, bsel ^ 1);
      asm volatile("s_waitcnt vmcnt(%0)" :: "n"(CPW) : "memory");
    } else {
      asm volatile("s_waitcnt vmcnt(0)" ::: "memory");
    }
    __builtin_amdgcn_s_barrier();
    __builtin_amdgcn_sched_barrier(0);
    const unsigned short* Ab = LDS + bsel * BUFSH;
    const unsigned short* Bb = Ab + TM * 64;
#pragma unroll
    for (int kk = 0; kk < 2; ++kk) {
      bf16x8 af[AM], bfr[AN];
#pragma unroll
      for (int i = 0; i < AM; ++i) {
        int row = wr * (AM * 16) + i * 16 + lo;
        unsigned by = (unsigned)(row * 128) + ((unsigned)(((kk * 4 + hi) ^ (row & 7))) << 4);
        af[i] = *(const bf16x8*)((const char*)Ab + by);
      }
#pragma unroll
      for (int j = 0; j < AN; ++j) {
        int row = wc * (AN * 16) + j * 16 + lo;
        unsigned by = (unsigned)(row * 128) + ((unsigned)(((kk * 4 + hi) ^ (row & 7))) << 4);
        bfr[j] = *(const bf16x8*)((const char*)Bb + by);
      }
      __builtin_amdgcn_s_setprio(1);
#pragma unroll
      for (int i = 0; i < AM; ++i)
#pragma unroll
        for (int j = 0; j < AN; ++j)
          acc[i][j] = __builtin_amdgcn_mfma_f32_16x16x32_bf16(af[i], bfr[j], acc[i][j], 0, 0, 0);
      __builtin_amdgcn_s_setprio(0);
    }
    __builtin_amdgcn_sched_barrier(0);
    __builtin_amdgcn_s_barrier();
  }

#pragma unroll
  for (int mi = 0; mi < AM; ++mi)
#pragma unroll
    for (int ni = 0; ni < AN; ++ni) {
      int row = m0 + wr * (AM * 16) + mi * 16 + hi * 4;
      int col = n0 + wc * (AN * 16) + ni * 16 + lo;
#pragma unroll
      for (int r = 0; r < 4; ++r) {
        float v = acc[mi][ni][r];
        size_t idx = (size_t)(row + r) * N + col;
        if (EPI == 0) {
          ((unsigned short*)C)[idx] = f2bf(v);
        } else if (EPI == 1) {
          ((float*)C)[idx] = v + res[idx];
        } else {
          ((unsigned short*)C)[idx] = f2bf(fmaxf(v, 0.0f));
        }
      }
    }
}

template <int TM, int TN, int EPI>
__global__ __launch_bounds__(256)
void gemm_bt(const unsigned short* __restrict__ A, const unsigned short* __restrict__ Bt,
             void* __restrict__ C, const float* __restrict__ res, int N, int K) {
  __shared__ __align__(16) unsigned short LDS[2 * (TM + TN) * 64];
  int f = blockIdx.y * gridDim.x + blockIdx.x;
  gemm_body<TM, TN, EPI>(f, gridDim.x, gridDim.x * gridDim.y, A, Bt, C, res, N, K, LDS);
}

// ---------------------------------------------------------------------------
// Mega prep: 10 weight transposes, enc f32->bf16, rp->u8 (identity), rmsnorm1.
// [0,4608) 8x 768x768; [4608,6912) wi; [6912,9216) wo2; [9216,12288) enc;
// [12288,13312) rp; [13312,17408) rmsnorm(x).
// ---------------------------------------------------------------------------
struct PrepArgs {
  const float* wsrc[10];
  unsigned short* wdst[10];
  const float* enc; unsigned short* encb;
  const int* rp; unsigned char* rp8;
  const float* x; const float* snw; unsigned short* normb;
};

__global__ __launch_bounds__(256)
void prep_kernel(PrepArgs a) {
  __shared__ __align__(16) float tile[32][33];
  const int bid = blockIdx.x, tid = threadIdx.x;
  if (bid < 9216) {
    int widx, rem, Kd, Nd;
    if (bid < 4608)      { widx = bid / 576; rem = bid % 576;  Kd = 768;  Nd = 768;  }
    else if (bid < 6912) { widx = 8;         rem = bid - 4608; Kd = 768;  Nd = 3072; }
    else                 { widx = 9;         rem = bid - 6912; Kd = 3072; Nd = 768;  }
    const float* W = a.wsrc[widx];
    unsigned short* Wt = a.wdst[widx];
    int nb = Nd / 32;
    int n0 = (rem % nb) * 32, k0 = (rem / nb) * 32;
    int tx = tid & 31, ty = tid >> 5;
#pragma unroll
    for (int i = 0; i < 32; i += 8)
      tile[ty + i][tx] = W[(size_t)(k0 + ty + i) * Nd + n0 + tx];
    __syncthreads();
#pragma unroll
    for (int i = 0; i < 32; i += 8)
      Wt[(size_t)(n0 + ty + i) * Kd + k0 + tx] = f2bf(tile[tx][ty + i]);
  } else if (bid < 12288) {
    int i = (bid - 9216) * 256 + tid;
    float4 v = ((const float4*)a.enc)[i];
    unsigned long long pk = (unsigned long long)f2bf(v.x)
                          | ((unsigned long long)f2bf(v.y) << 16)
                          | ((unsigned long long)f2bf(v.z) << 32)
                          | ((unsigned long long)f2bf(v.w) << 48);
    *(unsigned long long*)(a.encb + (size_t)i * 4) = pk;
  } else if (bid < 13312) {
    int idx = (bid - 12288) * 256 + tid;          // 16 consecutive ints -> 16 bytes
    const int4* src = (const int4*)(a.rp + (size_t)idx * 16);
    int4 v0 = src[0], v1 = src[1], v2 = src[2], v3 = src[3];
    uint4 o;
    o.x = (v0.x & 31) | ((v0.y & 31) << 8) | ((v0.z & 31) << 16) | ((v0.w & 31) << 24);
    o.y = (v1.x & 31) | ((v1.y & 31) << 8) | ((v1.z & 31) << 16) | ((v1.w & 31) << 24);
    o.z = (v2.x & 31) | ((v2.y & 31) << 8) | ((v2.z & 31) << 16) | ((v2.w & 31) << 24);
    o.w = (v3.x & 31) | ((v3.y & 31) << 8) | ((v3.z & 31) << 16) | ((v3.w & 31) << 24);
    ((uint4*)a.rp8)[idx] = o;
  } else {
    int row = bid - 13312;
    const float* r = a.x + (size_t)row * 768;
    float x0 = r[tid], x1 = r[tid + 256], x2 = r[tid + 512];
    float s = x0 * x0 + x1 * x1 + x2 * x2;
#pragma unroll
    for (int off = 32; off > 0; off >>= 1) s += __shfl_xor(s, off);
    float* wsm = &tile[0][0];
    int lane = tid & 63, wvv = tid >> 6;
    if (lane == 0) wsm[wvv] = s;
    __syncthreads();
    float tot = wsm[0] + wsm[1] + wsm[2] + wsm[3];
    float rinv = rsqrtf(tot * (1.0f / 768.0f) + 1e-6f);
    unsigned short* o = a.normb + (size_t)row * 768;
    o[tid]       = f2bf(x0 * rinv * a.snw[tid]);
    o[tid + 256] = f2bf(x1 * rinv * a.snw[tid + 256]);
    o[tid + 512] = f2bf(x2 * rinv * a.snw[tid + 512]);
  }
}

// ---------------------------------------------------------------------------
// RMSNorm standalone (stages 2 & 3)
// ---------------------------------------------------------------------------
__global__ __launch_bounds__(256)
void rmsnorm_kernel(const float* __restrict__ in, const float* __restrict__ w,
                    unsigned short* __restrict__ out) {
  int row = blockIdx.x, tid = threadIdx.x;
  const float* r = in + (size_t)row * 768;
  float x0 = r[tid], x1 = r[tid + 256], x2 = r[tid + 512];
  float s = x0 * x0 + x1 * x1 + x2 * x2;
#pragma unroll
  for (int off = 32; off > 0; off >>= 1) s += __shfl_xor(s, off);
  __shared__ float ws_[4];
  int lane = tid & 63, wv = tid >> 6;
  if (lane == 0) ws_[wv] = s;
  __syncthreads();
  float tot = ws_[0] + ws_[1] + ws_[2] + ws_[3];
  float rinv = rsqrtf(tot * (1.0f / 768.0f) + 1e-6f);
  unsigned short* o = out + (size_t)row * 768;
  o[tid]       = f2bf(x0 * rinv * w[tid]);
  o[tid + 256] = f2bf(x1 * rinv * w[tid + 256]);
  o[tid + 512] = f2bf(x2 * rinv * w[tid + 512]);
}

// ---------------------------------------------------------------------------
// Stage-1 mega kernel: QKV GEMM [0,576) + crossKV GEMM [576,960) +
// pos_bias/out2 writer [960,5056). BW blocks overlap the MFMA blocks.
// ---------------------------------------------------------------------------
struct Stage1Args {
  const unsigned short *normb, *wqkvT, *encb, *wckvT;
  unsigned short *qkv, *ckv;
  const int* rp; const float* rel;
  float *out1, *out2;
};

__global__ __launch_bounds__(256)
void stage1_kernel(Stage1Args a) {
  __shared__ __align__(16) unsigned short LDS[32768];
  const int bid = blockIdx.x, tid = threadIdx.x;
  if (bid < 576) {
    gemm_body<128, 128, 0>(bid, 18, 576, a.normb, a.wqkvT, a.qkv, nullptr, 2304, 768, LDS);
  } else if (bid < 960) {
    gemm_body<128, 128, 0>(bid - 576, 12, 384, a.encb, a.wckvT, a.ckv, nullptr, 1536, 768, LDS);
  } else {
    const int p = bid - 960;
    float* rl = (float*)LDS;
    for (int i = tid; i < 384; i += 256) rl[i] = a.rel[i];
    __syncthreads();
    int t = p >> 1;
    int s = (p & 1) * 1024 + tid * 4;
    int4 nb = *(const int4*)(a.rp + (size_t)t * 2048 + s);
#pragma unroll
    for (int h = 0; h < 12; ++h) {
      float4 v = make_float4(rl[nb.x * 12 + h], rl[nb.y * 12 + h],
                             rl[nb.z * 12 + h], rl[nb.w * 12 + h]);
      *(float4*)(a.out1 + ((size_t)h * 2048 + t) * 2048 + s) = v;
    }
    size_t zbase = ((size_t)p * 256 + tid) * 8;
    float4 z = make_float4(0.f, 0.f, 0.f, 0.f);
    *(float4*)(a.out2 + zbase)     = z;
    *(float4*)(a.out2 + zbase + 4) = z;
  }
}

// ---------------------------------------------------------------------------
// Both V transposes in one launch: z = b + 2*which.
// which 0: self V (qkv+1536, stride 2304) -> vT1; 1: cross V (ckv+768, 1536) -> vT2
// ---------------------------------------------------------------------------
__global__ __launch_bounds__(256)
void transpose_both_kernel(const unsigned short* __restrict__ v1,
                           const unsigned short* __restrict__ v2,
                           unsigned short* __restrict__ vT1,
                           unsigned short* __restrict__ vT2) {
  __shared__ __align__(16) unsigned short tile[64][72];
  int which = blockIdx.z >> 1, b = blockIdx.z & 1;
  const unsigned short* vin = which ? v2 : v1;
  int stride = which ? 1536 : 2304;
  unsigned short* vT = which ? vT2 : vT1;
  int t0 = blockIdx.x * 64, h = blockIdx.y;
  int tid = threadIdx.x;
  {
    int tl = tid >> 2, d0 = (tid & 3) * 16;
    const unsigned short* src = vin + (size_t)(b * 2048 + t0 + tl) * stride + h * 64 + d0;
    *(bf16x8*)&tile[tl][d0]     = *(const bf16x8*)src;
    *(bf16x8*)&tile[tl][d0 + 8] = *(const bf16x8*)(src + 8);
  }
  __syncthreads();
  {
    int d = tid >> 2, t1 = (tid & 3) * 16;
    unsigned short tmp[16] __attribute__((aligned(16)));
#pragma unroll
    for (int j = 0; j < 16; ++j) tmp[j] = tile[t1 + j][d];
    unsigned short* dst = vT + ((size_t)((b * 12 + h) * 64 + d)) * 2048 + t0 + t1;
    *(bf16x8*)dst       = *(bf16x8*)&tmp[0];
    *(bf16x8*)(dst + 8) = *(bf16x8*)&tmp[8];
  }
}

// ---------------------------------------------------------------------------
// Attention q-tile compute (swapped operands; lane owns q = lane&15).
// Defer-max: skip O-rescale when running max unchanged.
// ---------------------------------------------------------------------------
template <bool SELF>
__device__ __forceinline__ void attn_qcomp(
    const bf16x8& qf0, const bf16x8& qf1, f32x4* Oc, float& m_, float& l_,
    const unsigned char* rt, const float* rel_l, int qrow, bool edge, int s0,
    const unsigned short* Kb, const unsigned short* Vb, int lo, int hi) {
  f32x4 S[4];
  __builtin_amdgcn_s_setprio(1);
#pragma unroll
  for (int ct = 0; ct < 4; ++ct) {
    int krow = ct * 16 + lo;
    unsigned by0 = ((unsigned)(krow * 128 + hi * 16))      ^ ((unsigned)(krow & 7) << 4);
    unsigned by1 = ((unsigned)(krow * 128 + 64 + hi * 16)) ^ ((unsigned)(krow & 7) << 4);
    bf16x8 kf0 = *(const bf16x8*)((const char*)Kb + by0);
    bf16x8 kf1 = *(const bf16x8*)((const char*)Kb + by1);
    f32x4 sa = f32x4{0.f, 0.f, 0.f, 0.f};
    sa = __builtin_amdgcn_mfma_f32_16x16x32_bf16(kf0, qf0, sa, 0, 0, 0);
    sa = __builtin_amdgcn_mfma_f32_16x16x32_bf16(kf1, qf1, sa, 0, 0, 0);
    S[ct] = sa;
  }
  __builtin_amdgcn_s_setprio(0);

  if constexpr (SELF) {
#pragma unroll
    for (int ct = 0; ct < 4; ++ct) {
      unsigned nb4 = *(const unsigned*)&rt[lo * 64 + ct * 16 + hi * 4];
#pragma unroll
      for (int r = 0; r < 4; ++r) {
        int s = s0 + ct * 16 + hi * 4 + r;
        float sc = S[ct][r] + rel_l[(nb4 >> (8 * r)) & 31u];
        if (edge && s > qrow) sc = -1e30f;
        S[ct][r] = sc;
      }
    }
  }

  float tm = S[0][0];
#pragma unroll
  for (int ct = 0; ct < 4; ++ct)
#pragma unroll
    for (int r = 0; r < 4; ++r) tm = fmaxf(tm, S[ct][r]);
  tm = fmaxf(tm, __shfl_xor(tm, 16));
  tm = fmaxf(tm, __shfl_xor(tm, 32));
  float mn = fmaxf(m_, tm);
  float alpha = __expf(m_ - mn);
  float rs = 0.f;
#pragma unroll
  for (int ct = 0; ct < 4; ++ct)
#pragma unroll
    for (int r = 0; r < 4; ++r) { float e = __expf(S[ct][r] - mn); S[ct][r] = e; rs += e; }
  rs += __shfl_xor(rs, 16);
  rs += __shfl_xor(rs, 32);
  l_ = l_ * alpha + rs;
  if (tm > m_) {                      // defer-max: alpha==1 -> skip rescale
#pragma unroll
    for (int dt = 0; dt < 4; ++dt)
#pragma unroll
      for (int r = 0; r < 4; ++r) Oc[dt][r] *= alpha;
  }
  m_ = mn;

  short4v pf[4];
#pragma unroll
  for (int ct = 0; ct < 4; ++ct) {
    union { unsigned u[2]; short4v s; } cv;
    cv.u[0] = cvt_pk_bf16(S[ct][0], S[ct][1]);
    cv.u[1] = cvt_pk_bf16(S[ct][2], S[ct][3]);
    pf[ct] = cv.s;
  }

  __builtin_amdgcn_s_setprio(1);
#pragma unroll
  for (int dt = 0; dt < 4; ++dt) {
    int vrow = dt * 16 + lo;
#pragma unroll
    for (int ct = 0; ct < 4; ++ct) {
      unsigned vb = ((unsigned)(vrow * 128 + ct * 32 + hi * 8)) ^ ((unsigned)(vrow & 7) << 4);
      short4v vf = *(const short4v*)((const char*)Vb + vb);
      Oc[dt] = mfma16(vf, pf[ct], Oc[dt]);
    }
  }
  __builtin_amdgcn_s_setprio(0);
}

__device__ __forceinline__ void attn_store(f32x4* Oc, float l_, unsigned short* yr) {
  float inv = 1.0f / l_;
#pragma unroll
  for (int dt = 0; dt < 4; ++dt) {
    unsigned long long pk = (unsigned long long)f2bf(Oc[dt][0] * inv)
                          | ((unsigned long long)f2bf(Oc[dt][1] * inv) << 16)
                          | ((unsigned long long)f2bf(Oc[dt][2] * inv) << 32)
                          | ((unsigned long long)f2bf(Oc[dt][3] * inv) << 48);
    *(unsigned long long*)(yr + dt * 16) = pk;
  }
}

// ---------------------------------------------------------------------------
// Self-attention: paired q-tiles (i, 31-i), causal + rel bias. grid (16,12,2)
// ---------------------------------------------------------------------------
__global__ __launch_bounds__(256)
void attn_self_kernel(const unsigned short* __restrict__ qp,   // qkv, stride 2304
                      const unsigned short* __restrict__ kp,   // qkv+768
                      const unsigned short* __restrict__ vT,
                      const unsigned char* __restrict__ rp8,
                      const float* __restrict__ rel_emb,
                      unsigned short* __restrict__ yp) {
  __shared__ __align__(16) unsigned short Kls[2][4096];
  __shared__ __align__(16) unsigned short Vls[2][4096];
  __shared__ __align__(16) unsigned char rp8t[2][8192];
  __shared__ float rel_l[32];

  const int tid = threadIdx.x, lane = tid & 63, wv = tid >> 6;
  const int lo = lane & 15, hi = lane >> 4;
  const int wg = xcd_swz(blockIdx.x + 16 * (blockIdx.y + 12 * blockIdx.z), 384);
  const int xq = wg & 15, h = (wg >> 4) % 12, b = (wg >> 4) / 12;
  const int qta = xq, qtb = 31 - xq;
  const int ntiles = qtb + 1;

  if (tid < 32) rel_l[tid] = rel_emb[tid * 12 + h];

  const int qA = qta * 64 + wv * 16 + lo;
  const int qB = qtb * 64 + wv * 16 + lo;
  const unsigned short* qrA = qp + (size_t)(b * T5_T + qA) * 2304 + h * 64 + hi * 8;
  const unsigned short* qrB = qp + (size_t)(b * T5_T + qB) * 2304 + h * 64 + hi * 8;
  const bf16x8 qa0 = *(const bf16x8*)qrA;
  const bf16x8 qa1 = *(const bf16x8*)(qrA + 32);
  const bf16x8 qb0 = *(const bf16x8*)qrB;
  const bf16x8 qb1 = *(const bf16x8*)(qrB + 32);

  f32x4 OA[4], OB[4];
  float mA = -3.0e38f, lA = 0.f, mB = -3.0e38f, lB = 0.f;
#pragma unroll
  for (int i = 0; i < 4; ++i) { OA[i] = f32x4{0.f, 0.f, 0.f, 0.f}; OB[i] = f32x4{0.f, 0.f, 0.f, 0.f}; }

  const int krr = lane >> 3;
  const int kd0 = ((lane & 7) ^ krr) * 8;

  auto stage = [&](int kt, int bsel) {
    const int s0 = kt * 64;
#pragma unroll
    for (int j = 0; j < 2; ++j) {
      int c = wv * 2 + j;
      int rr = c * 8 + krr;
      load_lds16(kp + (size_t)(b * 2048 + s0 + rr) * 2304 + h * 64 + kd0, &Kls[bsel][c * 512]);
      load_lds16(vT + (size_t)((b * 12 + h) * 64 + rr) * 2048 + s0 + kd0,  &Vls[bsel][c * 512]);
    }
    load_lds16(rp8 + (size_t)(qtb * 64 + wv * 16 + (lane >> 2)) * 2048 + s0 + (lane & 3) * 16,
               &rp8t[bsel][4096 + wv * 1024]);
    if (kt <= qta)
      load_lds16(rp8 + (size_t)(qta * 64 + wv * 16 + (lane >> 2)) * 2048 + s0 + (lane & 3) * 16,
                 &rp8t[bsel][wv * 1024]);
  };

  stage(0, 0);

  for (int kt = 0; kt < ntiles; ++kt) {
    const int bsel = kt & 1;
    const int s0 = kt * 64;
    asm volatile("s_waitcnt vmcnt(0)" ::: "memory");
    __syncthreads();
    if (kt + 1 < ntiles) stage(kt + 1, bsel ^ 1);

    const unsigned short* Kb = &Kls[bsel][0];
    const unsigned short* Vb = &Vls[bsel][0];

    if (kt <= qta)
      attn_qcomp<true>(qa0, qa1, OA, mA, lA, &rp8t[bsel][wv * 1024], rel_l, qA,
                       kt == qta, s0, Kb, Vb, lo, hi);
    attn_qcomp<true>(qb0, qb1, OB, mB, lB, &rp8t[bsel][4096 + wv * 1024], rel_l, qB,
                     kt == qtb, s0, Kb, Vb, lo, hi);
  }

#if !__has_builtin(__builtin_amdgcn_mfma_f32_16x16x16bf16_1k)
  asm volatile("s_nop 7\n\ts_nop 7" ::: );
#endif

  attn_store(OA, lA, yp + (size_t)(b * T5_T + qA) * 768 + h * 64 + hi * 4);
  attn_store(OB, lB, yp + (size_t)(b * T5_T + qB) * 768 + h * 64 + hi * 4);
}

// ---------------------------------------------------------------------------
// Cross-attention: single q-tile per block, no bias/mask. grid (32,12,2)
// ---------------------------------------------------------------------------
__global__ __launch_bounds__(256)
void attn_cross_kernel(const unsigned short* __restrict__ qp,   // cq, stride 768
                       const unsigned short* __restrict__ kp,   // ckv, stride 1536
                       const unsigned short* __restrict__ vT,
                       unsigned short* __restrict__ yp) {
  __shared__ __align__(16) unsigned short Kls[2][4096];
  __shared__ __align__(16) unsigned short Vls[2][4096];

  const int tid = threadIdx.x, lane = tid & 63, wv = tid >> 6;
  const int lo = lane & 15, hi = lane >> 4;
  const int wg = xcd_swz(blockIdx.x + 32 * (blockIdx.y + 12 * blockIdx.z), 768);
  const int xq = wg & 31, h = (wg >> 5) % 12, b = (wg >> 5) / 12;

  const int q = xq * 64 + wv * 16 + lo;
  const unsigned short* qr = qp + (size_t)(b * T5_T + q) * 768 + h * 64 + hi * 8;
  const bf16x8 qf0 = *(const bf16x8*)qr;
  const bf16x8 qf1 = *(const bf16x8*)(qr + 32);

  f32x4 Oc[4];
  float m_ = -3.0e38f, l_ = 0.f;
#pragma unroll
  for (int i = 0; i < 4; ++i) Oc[i] = f32x4{0.f, 0.f, 0.f, 0.f};

  const int krr = lane >> 3;
  const int kd0 = ((lane & 7) ^ krr) * 8;

  auto stage = [&](int kt, int bsel) {
    const int s0 = kt * 64;
#pragma unroll
    for (int j = 0; j < 2; ++j) {
      int c = wv * 2 + j;
      int rr = c * 8 + krr;
      load_lds16(kp + (size_t)(b * 2048 + s0 + rr) * 1536 + h * 64 + kd0, &Kls[bsel][c * 512]);
      load_lds16(vT + (size_t)((b * 12 + h) * 64 + rr) * 2048 + s0 + kd0, &Vls[bsel][c * 512]);
    }
  };

  stage(0, 0);

  for (int kt = 0; kt < 32; ++kt) {
    const int bsel = kt & 1;
    asm volatile("s_waitcnt vmcnt(0)" ::: "memory");
    __syncthreads();
    if (kt + 1 < 32) stage(kt + 1, bsel ^ 1);
    attn_qcomp<false>(qf0, qf1, Oc, m_, l_, nullptr, nullptr, 0, false, kt * 64,
                      &Kls[bsel][0], &Vls[bsel][0], lo, hi);
  }

#if !__has_builtin(__builtin_amdgcn_mfma_f32_16x16x16bf16_1k)
  asm volatile("s_nop 7\n\ts_nop 7" ::: );
#endif

  attn_store(Oc, l_, yp + (size_t)(b * T5_T + q) * 768 + h * 64 + hi * 4);
}

// ---------------------------------------------------------------------------
extern "C" void kernel_launch(void* const* d_in, const int* in_sizes, int n_in,
                              void* d_out, int out_size, void* d_ws, size_t ws_size,
                              hipStream_t stream) {
  (void)in_sizes; (void)n_in; (void)out_size; (void)ws_size;
  const float* x    = (const float*)d_in[0];
  const int*   rp   = (const int*)d_in[2];
  const float* enc  = (const float*)d_in[3];
  const float* sn_w = (const float*)d_in[5];
  const float* wq   = (const float*)d_in[6];
  const float* wk   = (const float*)d_in[7];
  const float* wvw  = (const float*)d_in[8];
  const float* wo   = (const float*)d_in[9];
  const float* rel  = (const float*)d_in[10];
  const float* cn_w = (const float*)d_in[11];
  const float* cwq  = (const float*)d_in[12];
  const float* cwk  = (const float*)d_in[13];
  const float* cwv  = (const float*)d_in[14];
  const float* cwo  = (const float*)d_in[15];
  const float* pn_w = (const float*)d_in[16];
  const float* wi   = (const float*)d_in[17];
  const float* wo2  = (const float*)d_in[18];

  float* out0 = (float*)d_out;
  float* out1 = out0 + (size_t)NROW * T5_D;
  float* out2 = out1 + (size_t)T5_H * T5_T * T5_T;

  char* ws = (char*)d_ws;
  size_t off = 0;
  auto alloc = [&](size_t bytes) { char* p = ws + off; off += (bytes + 255) & ~(size_t)255; return p; };
  unsigned short* wqkvT = (unsigned short*)alloc((size_t)2304 * 768 * 2);
  unsigned short* woT   = (unsigned short*)alloc((size_t)768 * 768 * 2);
  unsigned short* wckvT = (unsigned short*)alloc((size_t)1536 * 768 * 2);
  unsigned short* wcqT  = (unsigned short*)alloc((size_t)768 * 768 * 2);
  unsigned short* wcoT  = (unsigned short*)alloc((size_t)768 * 768 * 2);
  unsigned short* wiT   = (unsigned short*)alloc((size_t)3072 * 768 * 2);
  unsigned short* woT2  = (unsigned short*)alloc((size_t)768 * 3072 * 2);
  unsigned short* normb = (unsigned short*)alloc((size_t)NROW * 768 * 2);
  unsigned short* encb  = (unsigned short*)alloc((size_t)NROW * 768 * 2);
  unsigned short* ybuf  = (unsigned short*)alloc((size_t)NROW * 768 * 2);
  unsigned short* cq    = (unsigned short*)alloc((size_t)NROW * 768 * 2);
  float*          attn  = (float*)alloc((size_t)NROW * 768 * 4);
  unsigned char*  rp8p  = (unsigned char*)alloc((size_t)2048 * 2048);
  unsigned short* qkv   = (unsigned short*)alloc((size_t)NROW * 2304 * 2);
  unsigned short* ckv   = (unsigned short*)alloc((size_t)NROW * 1536 * 2);
  unsigned short* vT1   = (unsigned short*)alloc((size_t)24 * 64 * 2048 * 2);
  unsigned short* vT2   = (unsigned short*)alloc((size_t)24 * 64 * 2048 * 2);
  unsigned short* ffh   = (unsigned short*)alloc((size_t)NROW * 3072 * 2);

  dim3 blk(256);

  // prep mega: weight transposes + enc conv + rp pack + rmsnorm1
  {
    PrepArgs pa;
    pa.wsrc[0] = wq;  pa.wdst[0] = wqkvT;
    pa.wsrc[1] = wk;  pa.wdst[1] = wqkvT + 768 * 768;
    pa.wsrc[2] = wvw; pa.wdst[2] = wqkvT + 2 * 768 * 768;
    pa.wsrc[3] = wo;  pa.wdst[3] = woT;
    pa.wsrc[4] = cwk; pa.wdst[4] = wckvT;
    pa.wsrc[5] = cwv; pa.wdst[5] = wckvT + 768 * 768;
    pa.wsrc[6] = cwq; pa.wdst[6] = wcqT;
    pa.wsrc[7] = cwo; pa.wdst[7] = wcoT;
    pa.wsrc[8] = wi;  pa.wdst[8] = wiT;
    pa.wsrc[9] = wo2; pa.wdst[9] = woT2;
    pa.enc = enc; pa.encb = encb; pa.rp = rp; pa.rp8 = rp8p;
    pa.x = x; pa.snw = sn_w; pa.normb = normb;
    prep_kernel<<<17408, blk, 0, stream>>>(pa);
  }

  // stage1 mega: QKV + crossKV GEMMs overlapped with pos_bias/out2 writes
  {
    Stage1Args sa;
    sa.normb = normb; sa.wqkvT = wqkvT; sa.encb = encb; sa.wckvT = wckvT;
    sa.qkv = qkv; sa.ckv = ckv; sa.rp = rp; sa.rel = rel;
    sa.out1 = out1; sa.out2 = out2;
    stage1_kernel<<<5056, blk, 0, stream>>>(sa);
  }

  // both V transposes
  transpose_both_kernel<<<dim3(32, 12, 4), blk, 0, stream>>>(qkv + 1536, ckv + 768, vT1, vT2);

  // self-attention (paired q-tiles)
  attn_self_kernel<<<dim3(16, 12, 2), blk, 0, stream>>>(qkv, qkv + 768, vT1, rp8p, rel, ybuf);
  // O-proj + residual -> attn (f32)
  gemm_bt<64, 64, 1><<<dim3(12, 64), blk, 0, stream>>>(ybuf, woT, attn, x, 768, 768);

  // cross-attention
  rmsnorm_kernel<<<NROW, blk, 0, stream>>>(attn, cn_w, normb);
  gemm_bt<64, 64, 0><<<dim3(12, 64), blk, 0, stream>>>(normb, wcqT, cq, nullptr, 768, 768);
  attn_cross_kernel<<<dim3(32, 12, 2), blk, 0, stream>>>(cq, ckv, vT2, ybuf);
  gemm_bt<64, 64, 1><<<dim3(12, 64), blk, 0, stream>>>(ybuf, wcoT, attn, attn, 768, 768);

  // FFN
  rmsnorm_kernel<<<NROW, blk, 0, stream>>>(attn, pn_w, normb);
  gemm_bt<128, 128, 2><<<dim3(24, 32), blk, 0, stream>>>(normb, wiT, ffh, nullptr, 3072, 768);
  gemm_bt<64, 64, 1><<<dim3(12, 64), blk, 0, stream>>>(ffh, woT2, out0, attn, 768, 3072);
}